// Round 2
// baseline (1076.217 us; speedup 1.0000x reference)
//
#include <hip/hip_runtime.h>

#define NN 50000
#define EE 400000
#define GG 500
#define F_IN 92
#define D_H 256
#define D_EMB 128

__device__ __forceinline__ float lrelu(float v) { return v > 0.f ? v : 0.01f * v; }

// ---------------- degree / dinv ----------------
__global__ void deg_kernel(const int* __restrict__ dst, float* __restrict__ deg, int E) {
    int e = blockIdx.x * blockDim.x + threadIdx.x;
    if (e < E) atomicAdd(&deg[dst[e]], 1.0f);
}
__global__ void dinv_kernel(float* __restrict__ deg, int n) {
    int i = blockIdx.x * blockDim.x + threadIdx.x;
    if (i < n) deg[i] = rsqrtf(deg[i] + 1.0f);   // +1 for self loop
}

// ---------------- tiled fp32 GEMM: out[M,Nd] = A[M,K] @ W[K,Nd] (+bias,lrelu) -------
template <bool BIAS_ACT>
__global__ __launch_bounds__(256) void gemm64(const float* __restrict__ A,
                                              const float* __restrict__ W,
                                              const float* __restrict__ bias,
                                              float* __restrict__ out,
                                              int M, int K, int Nd) {
    __shared__ float As[16][64];
    __shared__ float Bs[16][64];
    int tid = threadIdx.x;
    int tx = tid & 15, ty = tid >> 4;
    int m0 = blockIdx.x * 64, n0 = blockIdx.y * 64;
    float acc[4][4] = {};
    for (int k0 = 0; k0 < K; k0 += 16) {
        int ar = tid >> 2;            // 0..63  (tile row)
        int ac = (tid & 3) * 4;       // 0,4,8,12 (k group)
        int gm = m0 + ar;
#pragma unroll
        for (int j = 0; j < 4; ++j) {
            int gk = k0 + ac + j;
            float v = 0.f;
            if (gm < M && gk < K) v = A[(long)gm * K + gk];
            As[ac + j][ar] = v;
        }
        int bk = tid >> 4;            // 0..15
        int bn = (tid & 15) * 4;      // 0..60
        int gk = k0 + bk;
#pragma unroll
        for (int j = 0; j < 4; ++j) {
            int gn = n0 + bn + j;
            float v = 0.f;
            if (gk < K && gn < Nd) v = W[(long)gk * Nd + gn];
            Bs[bk][bn + j] = v;
        }
        __syncthreads();
#pragma unroll
        for (int kk = 0; kk < 16; ++kk) {
            float a4[4], b4[4];
            *(float4*)a4 = *(const float4*)&As[kk][ty * 4];
            *(float4*)b4 = *(const float4*)&Bs[kk][tx * 4];
#pragma unroll
            for (int i = 0; i < 4; ++i)
#pragma unroll
                for (int j = 0; j < 4; ++j) acc[i][j] += a4[i] * b4[j];
        }
        __syncthreads();
    }
#pragma unroll
    for (int i = 0; i < 4; ++i) {
        int gm = m0 + ty * 4 + i;
        if (gm >= M) continue;
#pragma unroll
        for (int j = 0; j < 4; ++j) {
            int gn = n0 + tx * 4 + j;
            if (gn >= Nd) continue;
            float v = acc[i][j];
            if constexpr (BIAS_ACT) {
                v += bias[gn];
                v = lrelu(v);
            }
            out[(long)gm * Nd + gn] = v;
        }
    }
}

// ---------------- edge scatter-add (one block per edge) ----------------
__global__ void edge_agg(const float* __restrict__ xw, const int* __restrict__ src,
                         const int* __restrict__ dst, const float* __restrict__ dinv,
                         float* __restrict__ agg, int E, int D) {
    int e = blockIdx.x;
    if (e >= E) return;
    int s = src[e], d = dst[e];
    float c = dinv[s] * dinv[d];
    int f = threadIdx.x;
    atomicAdd(&agg[(long)d * D + f], xw[(long)s * D + f] * c);
}

// ---------------- block reduction helper ----------------
template <int NW>
__device__ __forceinline__ float block_sum(float v, float* sm) {
#pragma unroll
    for (int off = 32; off; off >>= 1) v += __shfl_down(v, off);
    int wave = threadIdx.x >> 6, lane = threadIdx.x & 63;
    if (lane == 0) sm[wave] = v;
    __syncthreads();
    if (wave == 0) {
        float w = (lane < NW) ? sm[lane] : 0.f;
#pragma unroll
        for (int off = NW > 1 ? NW / 2 : 0; off; off >>= 1) w += __shfl_down(w, off);
        if (lane == 0) sm[0] = w;
    }
    __syncthreads();
    float r = sm[0];
    __syncthreads();
    return r;
}

// ---------------- self-loop + bias + LayerNorm + lrelu (+ L2 normalize) ----------------
template <int D, bool L2N>
__global__ __launch_bounds__(D) void post_ln(const float* __restrict__ agg,
                                             const float* __restrict__ xw,
                                             const float* __restrict__ dinv,
                                             const float* __restrict__ bias,
                                             const float* __restrict__ gamma,
                                             const float* __restrict__ beta,
                                             float* __restrict__ outf) {
    constexpr int NW = D / 64;
    __shared__ float sm[NW];
    int i = blockIdx.x;
    int f = threadIdx.x;
    float di = dinv[i];
    float x = agg[(long)i * D + f] + xw[(long)i * D + f] * di * di + bias[f];
    float mu = block_sum<NW>(x, sm) * (1.0f / D);
    float dx = x - mu;
    float var = block_sum<NW>(dx * dx, sm) * (1.0f / D);
    float y = dx * rsqrtf(var + 1e-5f) * gamma[f] + beta[f];
    y = lrelu(y);
    if constexpr (L2N) {
        float ss = block_sum<NW>(y * y, sm);
        float nrm = sqrtf(ss);
        y = y / fmaxf(nrm, 1e-12f);
    }
    outf[(long)i * D + f] = y;
}

// ---------------- global add pool ----------------
__global__ void pool_kernel(const float* __restrict__ ha, const int* __restrict__ batch,
                            float* __restrict__ hg) {
    int i = blockIdx.x;
    int f = threadIdx.x;  // 128
    atomicAdd(&hg[(long)batch[i] * D_EMB + f], ha[(long)i * D_EMB + f]);
}

// ---------------- MLP head: one block (64 threads) per graph ----------------
__global__ __launch_bounds__(64) void head_kernel(const float* __restrict__ hg,
                                                  const float* __restrict__ fc1W,
                                                  const float* __restrict__ fc1b,
                                                  const float* __restrict__ fc2W,
                                                  const float* __restrict__ fc2b,
                                                  float* __restrict__ out) {
    int r = blockIdx.x;
    int j = threadIdx.x;  // 0..63
    float acc = fc1b[j];
    for (int k = 0; k < D_EMB; ++k)
        acc += hg[(long)r * D_EMB + k] * fc1W[k * 64 + j];
    acc = lrelu(acc);
    float p = acc * fc2W[j];
#pragma unroll
    for (int off = 32; off; off >>= 1) p += __shfl_down(p, off);
    if (j == 0) out[r] = p + fc2b[0];
}

static inline size_t align256(size_t x) { return (x + 255) & ~(size_t)255; }

extern "C" void kernel_launch(void* const* d_in, const int* in_sizes, int n_in,
                              void* d_out, int out_size, void* d_ws, size_t ws_size,
                              hipStream_t stream) {
    const float* x     = (const float*)d_in[0];
    const int*   ei    = (const int*)d_in[1];   // [2,E]: src then dst
    const int*   batch = (const int*)d_in[2];
    const float* nfc_W = (const float*)d_in[3];
    const float* nfc_b = (const float*)d_in[4];
    const float* gn1_g = (const float*)d_in[5];
    const float* gn1_b = (const float*)d_in[6];
    const float* gc1_W = (const float*)d_in[7];
    const float* gc1_b = (const float*)d_in[8];
    const float* gn2_g = (const float*)d_in[9];
    const float* gn2_b = (const float*)d_in[10];
    const float* gc2_W = (const float*)d_in[11];
    const float* gc2_b = (const float*)d_in[12];
    const float* fc1_W = (const float*)d_in[13];
    const float* fc1_b = (const float*)d_in[14];
    const float* fc2_W = (const float*)d_in[15];
    const float* fc2_b = (const float*)d_in[16];

    char* ws = (char*)d_ws;
    size_t off = 0;
    float* dinv = (float*)(ws + off); off += align256((size_t)NN * 4);
    float* bufA = (float*)(ws + off); off += align256((size_t)NN * D_H * 4);
    float* bufB = (float*)(ws + off); off += align256((size_t)NN * D_H * 4);
    float* bufC = (float*)(ws + off); off += align256((size_t)NN * D_H * 4);
    float* hg   = (float*)(ws + off); off += align256((size_t)GG * D_EMB * 4);

    const int* src = ei;
    const int* dst = ei + EE;
    float* out_scores = (float*)d_out;            // [500]
    float* out_ha     = (float*)d_out + GG;       // [50000,128] fp32

    // 1) degrees -> dinv
    hipMemsetAsync(dinv, 0, (size_t)NN * 4, stream);
    deg_kernel<<<(EE + 255) / 256, 256, 0, stream>>>(dst, dinv, EE);
    dinv_kernel<<<(NN + 255) / 256, 256, 0, stream>>>(dinv, NN);

    // 2) ha = lrelu(x @ nfc_W + nfc_b)  [N, 256]
    gemm64<true><<<dim3((NN + 63) / 64, D_H / 64), 256, 0, stream>>>(
        x, nfc_W, nfc_b, bufA, NN, F_IN, D_H);

    // 3) conv1: xw = ha @ gc1_W  [N,256]
    gemm64<false><<<dim3((NN + 63) / 64, D_H / 64), 256, 0, stream>>>(
        bufA, gc1_W, nullptr, bufB, NN, D_H, D_H);
    hipMemsetAsync(bufC, 0, (size_t)NN * D_H * 4, stream);
    edge_agg<<<EE, D_H, 0, stream>>>(bufB, src, dst, dinv, bufC, EE, D_H);
    post_ln<D_H, false><<<NN, D_H, 0, stream>>>(bufC, bufB, dinv, gc1_b, gn1_g, gn1_b,
                                                bufA);

    // 4) conv2: xw = ha @ gc2_W  [N,128]
    gemm64<false><<<dim3((NN + 63) / 64, D_EMB / 64), 256, 0, stream>>>(
        bufA, gc2_W, nullptr, bufB, NN, D_H, D_EMB);
    hipMemsetAsync(bufC, 0, (size_t)NN * D_EMB * 4, stream);
    edge_agg<<<EE, D_EMB, 0, stream>>>(bufB, src, dst, dinv, bufC, EE, D_EMB);
    post_ln<D_EMB, true><<<NN, D_EMB, 0, stream>>>(bufC, bufB, dinv, gc2_b, gn2_g, gn2_b,
                                                   out_ha);

    // 5) pool + head
    hipMemsetAsync(hg, 0, (size_t)GG * D_EMB * 4, stream);
    pool_kernel<<<NN, D_EMB, 0, stream>>>(out_ha, batch, hg);
    head_kernel<<<GG, 64, 0, stream>>>(hg, fc1_W, fc1_b, fc2_W, fc2_b, out_scores);
}

// Round 3
// 725.668 us; speedup vs baseline: 1.4831x; 1.4831x over previous
//
#include <hip/hip_runtime.h>

#define NN 50000
#define EE 400000
#define GG 500
#define F_IN 92
#define D_H 256
#define D_EMB 128

__device__ __forceinline__ float lrelu(float v) { return v > 0.f ? v : 0.01f * v; }

// ---------------- degree count (int) ----------------
__global__ void count_kernel(const int* __restrict__ dst, int* __restrict__ cnt, int E) {
    int e = blockIdx.x * blockDim.x + threadIdx.x;
    if (e < E) atomicAdd(&cnt[dst[e]], 1);
}
__global__ void dinv_kernel(const int* __restrict__ cnt, float* __restrict__ dinv, int n) {
    int i = blockIdx.x * blockDim.x + threadIdx.x;
    if (i < n) dinv[i] = rsqrtf((float)cnt[i] + 1.0f);   // +1 for self loop
}

// ---------------- 3-kernel exclusive scan over cnt -> rowptr ----------------
__global__ void scan1(const int* __restrict__ cnt, int* __restrict__ excl,
                      int* __restrict__ bsum, int n) {
    __shared__ int sm[256];
    int i = blockIdx.x * 256 + threadIdx.x;
    int v = (i < n) ? cnt[i] : 0;
    sm[threadIdx.x] = v;
    __syncthreads();
#pragma unroll
    for (int off = 1; off < 256; off <<= 1) {
        int t = (threadIdx.x >= off) ? sm[threadIdx.x - off] : 0;
        __syncthreads();
        sm[threadIdx.x] += t;
        __syncthreads();
    }
    if (i < n) excl[i] = sm[threadIdx.x] - v;
    if (threadIdx.x == 255) bsum[blockIdx.x] = sm[255];
}
__global__ void scan2(int* __restrict__ bsum, int nb) {
    __shared__ int sm[256];
    int v = (threadIdx.x < nb) ? bsum[threadIdx.x] : 0;
    sm[threadIdx.x] = v;
    __syncthreads();
#pragma unroll
    for (int off = 1; off < 256; off <<= 1) {
        int t = (threadIdx.x >= off) ? sm[threadIdx.x - off] : 0;
        __syncthreads();
        sm[threadIdx.x] += t;
        __syncthreads();
    }
    if (threadIdx.x < nb) bsum[threadIdx.x] = sm[threadIdx.x] - v;  // exclusive
}
__global__ void scan3(int* __restrict__ rowptr, const int* __restrict__ bsum, int n, int E) {
    int i = blockIdx.x * 256 + threadIdx.x;
    if (i < n) rowptr[i] += bsum[blockIdx.x];
    if (i == 0) rowptr[n] = E;
}

// ---------------- scatter edges into CSR order ----------------
__global__ void scatter_kernel(const int* __restrict__ src, const int* __restrict__ dst,
                               const int* __restrict__ rowptr, int* __restrict__ cursor,
                               int* __restrict__ esrc, int E) {
    int e = blockIdx.x * blockDim.x + threadIdx.x;
    if (e >= E) return;
    int d = dst[e];
    int p = rowptr[d] + atomicAdd(&cursor[d], 1);
    esrc[p] = src[e];
}

// ------ tiled fp32 GEMM: out[M,Nd] = A[M,K] @ W[K,Nd] (+bias/lrelu | *rowscale) ------
template <bool BIAS_ACT, bool ROW_SCALE>
__global__ __launch_bounds__(256) void gemm64(const float* __restrict__ A,
                                              const float* __restrict__ W,
                                              const float* __restrict__ bias,
                                              const float* __restrict__ rscale,
                                              float* __restrict__ out,
                                              int M, int K, int Nd) {
    __shared__ float As[16][64];
    __shared__ float Bs[16][64];
    int tid = threadIdx.x;
    int tx = tid & 15, ty = tid >> 4;
    int m0 = blockIdx.x * 64, n0 = blockIdx.y * 64;
    float acc[4][4] = {};
    for (int k0 = 0; k0 < K; k0 += 16) {
        int ar = tid >> 2;
        int ac = (tid & 3) * 4;
        int gm = m0 + ar;
#pragma unroll
        for (int j = 0; j < 4; ++j) {
            int gk = k0 + ac + j;
            float v = 0.f;
            if (gm < M && gk < K) v = A[(long)gm * K + gk];
            As[ac + j][ar] = v;
        }
        int bk = tid >> 4;
        int bn = (tid & 15) * 4;
        int gk = k0 + bk;
#pragma unroll
        for (int j = 0; j < 4; ++j) {
            int gn = n0 + bn + j;
            float v = 0.f;
            if (gk < K && gn < Nd) v = W[(long)gk * Nd + gn];
            Bs[bk][bn + j] = v;
        }
        __syncthreads();
#pragma unroll
        for (int kk = 0; kk < 16; ++kk) {
            float a4[4], b4[4];
            *(float4*)a4 = *(const float4*)&As[kk][ty * 4];
            *(float4*)b4 = *(const float4*)&Bs[kk][tx * 4];
#pragma unroll
            for (int i = 0; i < 4; ++i)
#pragma unroll
                for (int j = 0; j < 4; ++j) acc[i][j] += a4[i] * b4[j];
        }
        __syncthreads();
    }
#pragma unroll
    for (int i = 0; i < 4; ++i) {
        int gm = m0 + ty * 4 + i;
        if (gm >= M) continue;
        float rs = ROW_SCALE ? rscale[gm] : 1.0f;
#pragma unroll
        for (int j = 0; j < 4; ++j) {
            int gn = n0 + tx * 4 + j;
            if (gn >= Nd) continue;
            float v = acc[i][j];
            if constexpr (BIAS_ACT) {
                v += bias[gn];
                v = lrelu(v);
            }
            if constexpr (ROW_SCALE) v *= rs;
            out[(long)gm * Nd + gn] = v;
        }
    }
}

// ---------------- CSR gather-aggregate: one wave per node ----------------
// agg[i,:] = sum_{k in [rowptr[i],rowptr[i+1])} y[esrc[k],:]    (y pre-scaled by dinv[src])
template <int D>
__global__ __launch_bounds__(256) void agg_csr(const float* __restrict__ y,
                                               const int* __restrict__ rowptr,
                                               const int* __restrict__ esrc,
                                               float* __restrict__ agg) {
    constexpr int V = D / 64;   // floats per lane (4 for 256, 2 for 128)
    int wave = threadIdx.x >> 6, lane = threadIdx.x & 63;
    int i = blockIdx.x * 4 + wave;
    if (i >= NN) return;
    int beg = rowptr[i], end = rowptr[i + 1];
    float acc[V] = {};
    for (int k = beg; k < end; ++k) {
        int s = esrc[k];
        const float* row = y + (long)s * D + lane * V;
        if constexpr (V == 4) {
            float4 r = *(const float4*)row;
            acc[0] += r.x; acc[1] += r.y; acc[2] += r.z; acc[3] += r.w;
        } else {
            float2 r = *(const float2*)row;
            acc[0] += r.x; acc[1] += r.y;
        }
    }
    float* o = agg + (long)i * D + lane * V;
    if constexpr (V == 4) {
        *(float4*)o = make_float4(acc[0], acc[1], acc[2], acc[3]);
    } else {
        *(float2*)o = make_float2(acc[0], acc[1]);
    }
}

// ---------------- block reduction helper ----------------
template <int NW>
__device__ __forceinline__ float block_sum(float v, float* sm) {
#pragma unroll
    for (int off = 32; off; off >>= 1) v += __shfl_down(v, off);
    int wave = threadIdx.x >> 6, lane = threadIdx.x & 63;
    if (lane == 0) sm[wave] = v;
    __syncthreads();
    if (wave == 0) {
        float w = (lane < NW) ? sm[lane] : 0.f;
#pragma unroll
        for (int off = NW > 1 ? NW / 2 : 0; off; off >>= 1) w += __shfl_down(w, off);
        if (lane == 0) sm[0] = w;
    }
    __syncthreads();
    float r = sm[0];
    __syncthreads();
    return r;
}

// -------- self-loop + bias + LayerNorm + lrelu (+ L2 normalize) --------
// x = (agg[i,f] + y[i,f]) * dinv[i] + bias[f]   where y = xw * dinv[src-row]
template <int D, bool L2N>
__global__ __launch_bounds__(D) void post_ln(const float* __restrict__ agg,
                                             const float* __restrict__ y,
                                             const float* __restrict__ dinv,
                                             const float* __restrict__ bias,
                                             const float* __restrict__ gamma,
                                             const float* __restrict__ beta,
                                             float* __restrict__ outf) {
    constexpr int NW = D / 64;
    __shared__ float sm[NW];
    int i = blockIdx.x;
    int f = threadIdx.x;
    float di = dinv[i];
    float x = (agg[(long)i * D + f] + y[(long)i * D + f]) * di + bias[f];
    float mu = block_sum<NW>(x, sm) * (1.0f / D);
    float dx = x - mu;
    float var = block_sum<NW>(dx * dx, sm) * (1.0f / D);
    float yv = dx * rsqrtf(var + 1e-5f) * gamma[f] + beta[f];
    yv = lrelu(yv);
    if constexpr (L2N) {
        float ss = block_sum<NW>(yv * yv, sm);
        float nrm = sqrtf(ss);
        yv = yv / fmaxf(nrm, 1e-12f);
    }
    outf[(long)i * D + f] = yv;
}

// ---------------- global add pool ----------------
__global__ void pool_kernel(const float* __restrict__ ha, const int* __restrict__ batch,
                            float* __restrict__ hg) {
    int i = blockIdx.x;
    int f = threadIdx.x;  // 128
    atomicAdd(&hg[(long)batch[i] * D_EMB + f], ha[(long)i * D_EMB + f]);
}

// ---------------- MLP head: one block (64 threads) per graph ----------------
__global__ __launch_bounds__(64) void head_kernel(const float* __restrict__ hg,
                                                  const float* __restrict__ fc1W,
                                                  const float* __restrict__ fc1b,
                                                  const float* __restrict__ fc2W,
                                                  const float* __restrict__ fc2b,
                                                  float* __restrict__ out) {
    int r = blockIdx.x;
    int j = threadIdx.x;  // 0..63
    float acc = fc1b[j];
    for (int k = 0; k < D_EMB; ++k)
        acc += hg[(long)r * D_EMB + k] * fc1W[k * 64 + j];
    acc = lrelu(acc);
    float p = acc * fc2W[j];
#pragma unroll
    for (int off = 32; off; off >>= 1) p += __shfl_down(p, off);
    if (j == 0) out[r] = p + fc2b[0];
}

static inline size_t align256(size_t x) { return (x + 255) & ~(size_t)255; }

extern "C" void kernel_launch(void* const* d_in, const int* in_sizes, int n_in,
                              void* d_out, int out_size, void* d_ws, size_t ws_size,
                              hipStream_t stream) {
    const float* x     = (const float*)d_in[0];
    const int*   ei    = (const int*)d_in[1];   // [2,E]: src then dst
    const int*   batch = (const int*)d_in[2];
    const float* nfc_W = (const float*)d_in[3];
    const float* nfc_b = (const float*)d_in[4];
    const float* gn1_g = (const float*)d_in[5];
    const float* gn1_b = (const float*)d_in[6];
    const float* gc1_W = (const float*)d_in[7];
    const float* gc1_b = (const float*)d_in[8];
    const float* gn2_g = (const float*)d_in[9];
    const float* gn2_b = (const float*)d_in[10];
    const float* gc2_W = (const float*)d_in[11];
    const float* gc2_b = (const float*)d_in[12];
    const float* fc1_W = (const float*)d_in[13];
    const float* fc1_b = (const float*)d_in[14];
    const float* fc2_W = (const float*)d_in[15];
    const float* fc2_b = (const float*)d_in[16];

    char* ws = (char*)d_ws;
    size_t off = 0;
    float* dinv   = (float*)(ws + off); off += align256((size_t)NN * 4);
    int*   cnt    = (int*)(ws + off);   off += align256((size_t)NN * 4);
    int*   rowptr = (int*)(ws + off);   off += align256((size_t)(NN + 1) * 4);
    int*   cursor = (int*)(ws + off);   off += align256((size_t)NN * 4);
    int*   bsum   = (int*)(ws + off);   off += align256((size_t)256 * 4);
    int*   esrc   = (int*)(ws + off);   off += align256((size_t)EE * 4);
    float* bufA   = (float*)(ws + off); off += align256((size_t)NN * D_H * 4);
    float* bufB   = (float*)(ws + off); off += align256((size_t)NN * D_H * 4);
    float* bufC   = (float*)(ws + off); off += align256((size_t)NN * D_H * 4);
    float* hg     = (float*)(ws + off); off += align256((size_t)GG * D_EMB * 4);

    const int* src = ei;
    const int* dst = ei + EE;
    float* out_scores = (float*)d_out;            // [500]
    float* out_ha     = (float*)d_out + GG;       // [50000,128] fp32

    const int NB = (NN + 255) / 256;              // 196 scan blocks

    // 1) CSR build: degrees -> dinv; exclusive scan -> rowptr; scatter
    hipMemsetAsync(cnt, 0, (size_t)NN * 4, stream);
    hipMemsetAsync(cursor, 0, (size_t)NN * 4, stream);
    count_kernel<<<(EE + 255) / 256, 256, 0, stream>>>(dst, cnt, EE);
    dinv_kernel<<<NB, 256, 0, stream>>>(cnt, dinv, NN);
    scan1<<<NB, 256, 0, stream>>>(cnt, rowptr, bsum, NN);
    scan2<<<1, 256, 0, stream>>>(bsum, NB);
    scan3<<<NB, 256, 0, stream>>>(rowptr, bsum, NN, EE);
    scatter_kernel<<<(EE + 255) / 256, 256, 0, stream>>>(src, dst, rowptr, cursor, esrc, EE);

    // 2) ha = lrelu(x @ nfc_W + nfc_b)  [N, 256]
    gemm64<true, false><<<dim3((NN + 63) / 64, D_H / 64), 256, 0, stream>>>(
        x, nfc_W, nfc_b, nullptr, bufA, NN, F_IN, D_H);

    // 3) conv1: y = (ha @ gc1_W) * dinv[row]  [N,256]; agg = CSR-sum; LN
    gemm64<false, true><<<dim3((NN + 63) / 64, D_H / 64), 256, 0, stream>>>(
        bufA, gc1_W, nullptr, dinv, bufB, NN, D_H, D_H);
    agg_csr<D_H><<<(NN + 3) / 4, 256, 0, stream>>>(bufB, rowptr, esrc, bufC);
    post_ln<D_H, false><<<NN, D_H, 0, stream>>>(bufC, bufB, dinv, gc1_b, gn1_g, gn1_b,
                                                bufA);

    // 4) conv2: y = (ha @ gc2_W) * dinv[row]  [N,128]; agg; LN + L2 normalize
    gemm64<false, true><<<dim3((NN + 63) / 64, D_EMB / 64), 256, 0, stream>>>(
        bufA, gc2_W, nullptr, dinv, bufB, NN, D_H, D_EMB);
    agg_csr<D_EMB><<<(NN + 3) / 4, 256, 0, stream>>>(bufB, rowptr, esrc, bufC);
    post_ln<D_EMB, true><<<NN, D_EMB, 0, stream>>>(bufC, bufB, dinv, gc2_b, gn2_g, gn2_b,
                                                   out_ha);

    // 5) pool + head
    hipMemsetAsync(hg, 0, (size_t)GG * D_EMB * 4, stream);
    pool_kernel<<<NN, D_EMB, 0, stream>>>(out_ha, batch, hg);
    head_kernel<<<GG, 64, 0, stream>>>(hg, fc1_W, fc1_b, fc2_W, fc2_b, out_scores);
}

// Round 4
// 422.314 us; speedup vs baseline: 2.5484x; 1.7183x over previous
//
#include <hip/hip_runtime.h>

#define NN 50000
#define EE 400000
#define GG 500
#define F_IN 92
#define KP1 96      // F_IN padded to multiple of 32
#define D_H 256
#define D_EMB 128

typedef __attribute__((ext_vector_type(8))) short short8_t;
typedef __attribute__((ext_vector_type(4))) float floatx4;

__device__ __forceinline__ float lrelu(float v) { return v > 0.f ? v : 0.01f * v; }
__device__ __forceinline__ float b2f(unsigned short u) {
    union { unsigned int u; float f; } x; x.u = (unsigned int)u << 16; return x.f;
}
__device__ __forceinline__ unsigned short f2b(float v) {
    union { float f; unsigned int u; } x; x.f = v;
    unsigned int r = x.u + 0x7FFFu + ((x.u >> 16) & 1u);   // RNE
    return (unsigned short)(r >> 16);
}

// ---------------- degree count / dinv ----------------
__global__ void count_kernel(const int* __restrict__ dst, int* __restrict__ cnt, int E) {
    int e = blockIdx.x * blockDim.x + threadIdx.x;
    if (e < E) atomicAdd(&cnt[dst[e]], 1);
}
__global__ void dinv_kernel(const int* __restrict__ cnt, float* __restrict__ dinv, int n) {
    int i = blockIdx.x * blockDim.x + threadIdx.x;
    if (i < n) dinv[i] = rsqrtf((float)cnt[i] + 1.0f);   // +1 self loop
}

// ---------------- 3-kernel exclusive scan -> rowptr ----------------
__global__ void scan1(const int* __restrict__ cnt, int* __restrict__ excl,
                      int* __restrict__ bsum, int n) {
    __shared__ int sm[256];
    int i = blockIdx.x * 256 + threadIdx.x;
    int v = (i < n) ? cnt[i] : 0;
    sm[threadIdx.x] = v;
    __syncthreads();
#pragma unroll
    for (int off = 1; off < 256; off <<= 1) {
        int t = (threadIdx.x >= off) ? sm[threadIdx.x - off] : 0;
        __syncthreads();
        sm[threadIdx.x] += t;
        __syncthreads();
    }
    if (i < n) excl[i] = sm[threadIdx.x] - v;
    if (threadIdx.x == 255) bsum[blockIdx.x] = sm[255];
}
__global__ void scan2(int* __restrict__ bsum, int nb) {
    __shared__ int sm[256];
    int v = (threadIdx.x < nb) ? bsum[threadIdx.x] : 0;
    sm[threadIdx.x] = v;
    __syncthreads();
#pragma unroll
    for (int off = 1; off < 256; off <<= 1) {
        int t = (threadIdx.x >= off) ? sm[threadIdx.x - off] : 0;
        __syncthreads();
        sm[threadIdx.x] += t;
        __syncthreads();
    }
    if (threadIdx.x < nb) bsum[threadIdx.x] = sm[threadIdx.x] - v;
}
__global__ void scan3(int* __restrict__ rowptr, const int* __restrict__ bsum, int n, int E) {
    int i = blockIdx.x * 256 + threadIdx.x;
    if (i < n) rowptr[i] += bsum[blockIdx.x];
    if (i == 0) rowptr[n] = E;
}
__global__ void scatter_kernel(const int* __restrict__ src, const int* __restrict__ dst,
                               const int* __restrict__ rowptr, int* __restrict__ cursor,
                               int* __restrict__ esrc, int E) {
    int e = blockIdx.x * blockDim.x + threadIdx.x;
    if (e >= E) return;
    int d = dst[e];
    int p = rowptr[d] + atomicAdd(&cursor[d], 1);
    esrc[p] = src[e];
}

// ---------------- prep casts ----------------
__global__ void cast_pad_x(const float* __restrict__ x, unsigned short* __restrict__ xb) {
    long i = (long)blockIdx.x * blockDim.x + threadIdx.x;
    if (i >= (long)NN * KP1) return;
    int row = (int)(i / KP1), col = (int)(i % KP1);
    float v = (col < F_IN) ? x[(long)row * F_IN + col] : 0.f;
    xb[i] = f2b(v);
}
// Wt[n][k] = W[k][n], zero-padded to Kp
__global__ void castT_W(const float* __restrict__ W, unsigned short* __restrict__ Wt,
                        int K, int Nd, int Kp) {
    int i = blockIdx.x * blockDim.x + threadIdx.x;
    if (i >= Nd * Kp) return;
    int n = i / Kp, k = i % Kp;
    Wt[i] = f2b(k < K ? W[(long)k * Nd + n] : 0.f);
}

// ---------------- bf16 MFMA GEMM: out[M,Nd] = A[M,Ka] @ Wt[Nd,Ka]^T ----------------
// 64x64 block tile, 4 waves, each wave: 16 rows x 64 cols via 4x 16x16x32 MFMA per K-tile.
template <bool BIAS_ACT, bool ROW_SCALE>
__global__ __launch_bounds__(256) void gemm_mfma(const unsigned short* __restrict__ A,
                                                 const unsigned short* __restrict__ Wt,
                                                 const float* __restrict__ bias,
                                                 const float* __restrict__ rscale,
                                                 unsigned short* __restrict__ out,
                                                 int M, int Ka, int Nd) {
    __shared__ unsigned short As[64][40];   // +8 pad: stride 20 banks breaks pow2 aliasing
    __shared__ unsigned short Bs[64][40];
    int tid = threadIdx.x;
    int wave = tid >> 6, lane = tid & 63;
    int lm = lane & 15, lk = lane >> 4;     // fragment row/col, k-group
    int m0 = blockIdx.x * 64, n0 = blockIdx.y * 64;
    int sr = tid >> 2, sk = (tid & 3) * 8;  // staging row, k-offset
    int gmS = m0 + sr;
    const unsigned short* Arow = A + (long)gmS * Ka + sk;
    const unsigned short* Brow = Wt + (long)(n0 + sr) * Ka + sk;
    floatx4 acc[4] = {};
    for (int k0 = 0; k0 < Ka; k0 += 32) {
        uint4 av = make_uint4(0, 0, 0, 0);
        if (gmS < M) av = *(const uint4*)(Arow + k0);
        uint4 bv = *(const uint4*)(Brow + k0);
        __syncthreads();                    // previous iter's reads done
        *(uint4*)&As[sr][sk] = av;
        *(uint4*)&Bs[sr][sk] = bv;
        __syncthreads();
        short8_t af = *(const short8_t*)&As[wave * 16 + lm][lk * 8];
#pragma unroll
        for (int c = 0; c < 4; ++c) {
            short8_t bf = *(const short8_t*)&Bs[c * 16 + lm][lk * 8];
            acc[c] = __builtin_amdgcn_mfma_f32_16x16x32_bf16(af, bf, acc[c], 0, 0, 0);
        }
    }
    // C/D: row = lk*4 + r, col = lm  (per-16x16 tile)
#pragma unroll
    for (int r = 0; r < 4; ++r) {
        int gm = m0 + wave * 16 + lk * 4 + r;
        if (gm >= M) continue;
        float rs = ROW_SCALE ? rscale[gm] : 1.f;
#pragma unroll
        for (int c = 0; c < 4; ++c) {
            int gn = n0 + c * 16 + lm;
            float v = acc[c][r];
            if constexpr (BIAS_ACT) { v += bias[gn]; v = lrelu(v); }
            if constexpr (ROW_SCALE) v *= rs;
            out[(long)gm * Nd + gn] = f2b(v);
        }
    }
}

// ---------------- CSR gather-aggregate (bf16 rows, fp32 acc): one wave per node -------
template <int D>
__global__ __launch_bounds__(256) void agg_csr(const unsigned short* __restrict__ y,
                                               const int* __restrict__ rowptr,
                                               const int* __restrict__ esrc,
                                               float* __restrict__ agg) {
    constexpr int V = D / 64;   // 4 for 256, 2 for 128
    int wave = threadIdx.x >> 6, lane = threadIdx.x & 63;
    int i = blockIdx.x * 4 + wave;
    if (i >= NN) return;
    int beg = rowptr[i], end = rowptr[i + 1];
    float acc[V] = {};
    for (int k = beg; k < end; ++k) {
        int s = esrc[k];
        const unsigned short* row = y + (long)s * D + lane * V;
        if constexpr (V == 4) {
            ushort4 r = *(const ushort4*)row;
            acc[0] += b2f(r.x); acc[1] += b2f(r.y); acc[2] += b2f(r.z); acc[3] += b2f(r.w);
        } else {
            ushort2 r = *(const ushort2*)row;
            acc[0] += b2f(r.x); acc[1] += b2f(r.y);
        }
    }
    float* o = agg + (long)i * D + lane * V;
#pragma unroll
    for (int v = 0; v < V; ++v) o[v] = acc[v];
}

// ---------------- block reduction helper ----------------
template <int NW>
__device__ __forceinline__ float block_sum(float v, float* sm) {
#pragma unroll
    for (int off = 32; off; off >>= 1) v += __shfl_down(v, off);
    int wave = threadIdx.x >> 6, lane = threadIdx.x & 63;
    if (lane == 0) sm[wave] = v;
    __syncthreads();
    if (wave == 0) {
        float w = (lane < NW) ? sm[lane] : 0.f;
#pragma unroll
        for (int off = NW > 1 ? NW / 2 : 0; off; off >>= 1) w += __shfl_down(w, off);
        if (lane == 0) sm[0] = w;
    }
    __syncthreads();
    float r = sm[0];
    __syncthreads();
    return r;
}

// -------- self-loop + bias + LayerNorm + lrelu (+L2 norm); y is bf16, pre-scaled ------
template <int D, bool L2N, bool TOBF>
__global__ __launch_bounds__(D) void post_ln(const float* __restrict__ agg,
                                             const unsigned short* __restrict__ y,
                                             const float* __restrict__ dinv,
                                             const float* __restrict__ bias,
                                             const float* __restrict__ gamma,
                                             const float* __restrict__ beta,
                                             float* __restrict__ outf,
                                             unsigned short* __restrict__ outb) {
    constexpr int NW = D / 64;
    __shared__ float sm[NW];
    int i = blockIdx.x;
    int f = threadIdx.x;
    float di = dinv[i];
    float x = (agg[(long)i * D + f] + b2f(y[(long)i * D + f])) * di + bias[f];
    float mu = block_sum<NW>(x, sm) * (1.0f / D);
    float dx = x - mu;
    float var = block_sum<NW>(dx * dx, sm) * (1.0f / D);
    float yv = dx * rsqrtf(var + 1e-5f) * gamma[f] + beta[f];
    yv = lrelu(yv);
    if constexpr (L2N) {
        float ss = block_sum<NW>(yv * yv, sm);
        yv = yv / fmaxf(sqrtf(ss), 1e-12f);
    }
    if constexpr (TOBF) outb[(long)i * D + f] = f2b(yv);
    else                outf[(long)i * D + f] = yv;
}

// ---------------- global add pool ----------------
__global__ void pool_kernel(const float* __restrict__ ha, const int* __restrict__ batch,
                            float* __restrict__ hg) {
    int i = blockIdx.x;
    int f = threadIdx.x;  // 128
    atomicAdd(&hg[(long)batch[i] * D_EMB + f], ha[(long)i * D_EMB + f]);
}

// ---------------- MLP head ----------------
__global__ __launch_bounds__(64) void head_kernel(const float* __restrict__ hg,
                                                  const float* __restrict__ fc1W,
                                                  const float* __restrict__ fc1b,
                                                  const float* __restrict__ fc2W,
                                                  const float* __restrict__ fc2b,
                                                  float* __restrict__ out) {
    int r = blockIdx.x;
    int j = threadIdx.x;  // 0..63
    float acc = fc1b[j];
    for (int k = 0; k < D_EMB; ++k)
        acc += hg[(long)r * D_EMB + k] * fc1W[k * 64 + j];
    acc = lrelu(acc);
    float p = acc * fc2W[j];
#pragma unroll
    for (int off = 32; off; off >>= 1) p += __shfl_down(p, off);
    if (j == 0) out[r] = p + fc2b[0];
}

static inline size_t align256(size_t x) { return (x + 255) & ~(size_t)255; }

extern "C" void kernel_launch(void* const* d_in, const int* in_sizes, int n_in,
                              void* d_out, int out_size, void* d_ws, size_t ws_size,
                              hipStream_t stream) {
    const float* x     = (const float*)d_in[0];
    const int*   ei    = (const int*)d_in[1];
    const int*   batch = (const int*)d_in[2];
    const float* nfc_W = (const float*)d_in[3];
    const float* nfc_b = (const float*)d_in[4];
    const float* gn1_g = (const float*)d_in[5];
    const float* gn1_b = (const float*)d_in[6];
    const float* gc1_W = (const float*)d_in[7];
    const float* gc1_b = (const float*)d_in[8];
    const float* gn2_g = (const float*)d_in[9];
    const float* gn2_b = (const float*)d_in[10];
    const float* gc2_W = (const float*)d_in[11];
    const float* gc2_b = (const float*)d_in[12];
    const float* fc1_W = (const float*)d_in[13];
    const float* fc1_b = (const float*)d_in[14];
    const float* fc2_W = (const float*)d_in[15];
    const float* fc2_b = (const float*)d_in[16];

    typedef unsigned short u16;
    char* ws = (char*)d_ws;
    size_t off = 0;
    float* dinv   = (float*)(ws + off); off += align256((size_t)NN * 4);
    int*   cnt    = (int*)(ws + off);   off += align256((size_t)NN * 4);
    int*   rowptr = (int*)(ws + off);   off += align256((size_t)(NN + 1) * 4);
    int*   cursor = (int*)(ws + off);   off += align256((size_t)NN * 4);
    int*   bsum   = (int*)(ws + off);   off += align256((size_t)256 * 4);
    int*   esrc   = (int*)(ws + off);   off += align256((size_t)EE * 4);
    u16*   xb     = (u16*)(ws + off);   off += align256((size_t)NN * KP1 * 2);
    u16*   WtN    = (u16*)(ws + off);   off += align256((size_t)D_H * KP1 * 2);
    u16*   Wt1    = (u16*)(ws + off);   off += align256((size_t)D_H * D_H * 2);
    u16*   Wt2    = (u16*)(ws + off);   off += align256((size_t)D_EMB * D_H * 2);
    u16*   ha1b   = (u16*)(ws + off);   off += align256((size_t)NN * D_H * 2);
    u16*   y1b    = (u16*)(ws + off);   off += align256((size_t)NN * D_H * 2);
    float* aggf   = (float*)(ws + off); off += align256((size_t)NN * D_H * 4);
    u16*   ha2b   = (u16*)(ws + off);   off += align256((size_t)NN * D_H * 2);
    u16*   y2b    = (u16*)(ws + off);   off += align256((size_t)NN * D_EMB * 2);
    float* hg     = (float*)(ws + off); off += align256((size_t)GG * D_EMB * 4);

    const int* src = ei;
    const int* dst = ei + EE;
    float* out_scores = (float*)d_out;
    float* out_ha     = (float*)d_out + GG;

    const int NB = (NN + 255) / 256;
    const int MB = (NN + 63) / 64;   // 782

    // 1) CSR build + dinv
    hipMemsetAsync(cnt, 0, (size_t)NN * 4, stream);
    hipMemsetAsync(cursor, 0, (size_t)NN * 4, stream);
    count_kernel<<<(EE + 255) / 256, 256, 0, stream>>>(dst, cnt, EE);
    dinv_kernel<<<NB, 256, 0, stream>>>(cnt, dinv, NN);
    scan1<<<NB, 256, 0, stream>>>(cnt, rowptr, bsum, NN);
    scan2<<<1, 256, 0, stream>>>(bsum, NB);
    scan3<<<NB, 256, 0, stream>>>(rowptr, bsum, NN, EE);
    scatter_kernel<<<(EE + 255) / 256, 256, 0, stream>>>(src, dst, rowptr, cursor, esrc, EE);

    // 2) bf16 prep
    cast_pad_x<<<(int)(((long)NN * KP1 + 255) / 256), 256, 0, stream>>>(x, xb);
    castT_W<<<(D_H * KP1 + 255) / 256, 256, 0, stream>>>(nfc_W, WtN, F_IN, D_H, KP1);
    castT_W<<<(D_H * D_H + 255) / 256, 256, 0, stream>>>(gc1_W, Wt1, D_H, D_H, D_H);
    castT_W<<<(D_EMB * D_H + 255) / 256, 256, 0, stream>>>(gc2_W, Wt2, D_H, D_EMB, D_H);

    // 3) ha1 = lrelu(x @ nfc_W + b)   [N,256] bf16
    gemm_mfma<true, false><<<dim3(MB, D_H / 64), 256, 0, stream>>>(
        xb, WtN, nfc_b, nullptr, ha1b, NN, KP1, D_H);

    // 4) conv1: y1 = (ha1 @ gc1_W) * dinv[row]; agg; LN -> ha2 bf16
    gemm_mfma<false, true><<<dim3(MB, D_H / 64), 256, 0, stream>>>(
        ha1b, Wt1, nullptr, dinv, y1b, NN, D_H, D_H);
    agg_csr<D_H><<<(NN + 3) / 4, 256, 0, stream>>>(y1b, rowptr, esrc, aggf);
    post_ln<D_H, false, true><<<NN, D_H, 0, stream>>>(aggf, y1b, dinv, gc1_b, gn1_g, gn1_b,
                                                      nullptr, ha2b);

    // 5) conv2: y2 = (ha2 @ gc2_W) * dinv[row]; agg; LN + L2 -> out_ha fp32
    gemm_mfma<false, true><<<dim3(MB, D_EMB / 64), 256, 0, stream>>>(
        ha2b, Wt2, nullptr, dinv, y2b, NN, D_H, D_EMB);
    agg_csr<D_EMB><<<(NN + 3) / 4, 256, 0, stream>>>(y2b, rowptr, esrc, aggf);
    post_ln<D_EMB, true, false><<<NN, D_EMB, 0, stream>>>(aggf, y2b, dinv, gc2_b, gn2_g, gn2_b,
                                                          out_ha, nullptr);

    // 6) pool + head
    hipMemsetAsync(hg, 0, (size_t)GG * D_EMB * 4, stream);
    pool_kernel<<<NN, D_EMB, 0, stream>>>(out_ha, batch, hg);
    head_kernel<<<GG, 64, 0, stream>>>(hg, fc1_W, fc1_b, fc2_W, fc2_b, out_scores);
}

// Round 5
// 337.723 us; speedup vs baseline: 3.1867x; 1.2505x over previous
//
#include <hip/hip_runtime.h>

#define NN 50000
#define EE 400000
#define GG 500
#define F_IN 92
#define KP1 96      // F_IN padded to multiple of 32
#define D_H 256
#define D_EMB 128

typedef __attribute__((ext_vector_type(8))) short short8_t;
typedef __attribute__((ext_vector_type(4))) float floatx4;

__device__ __forceinline__ float lrelu(float v) { return v > 0.f ? v : 0.01f * v; }
__device__ __forceinline__ float b2f(unsigned short u) {
    union { unsigned int u; float f; } x; x.u = (unsigned int)u << 16; return x.f;
}
__device__ __forceinline__ unsigned short f2b(float v) {
    union { float f; unsigned int u; } x; x.f = v;
    unsigned int r = x.u + 0x7FFFu + ((x.u >> 16) & 1u);   // RNE
    return (unsigned short)(r >> 16);
}
__device__ __forceinline__ float wave_allsum(float v) {
#pragma unroll
    for (int m = 1; m < 64; m <<= 1) v += __shfl_xor(v, m);
    return v;
}

// ---------------- degree count / dinv ----------------
__global__ void count_kernel(const int* __restrict__ dst, int* __restrict__ cnt, int E) {
    int e = blockIdx.x * blockDim.x + threadIdx.x;
    if (e < E) atomicAdd(&cnt[dst[e]], 1);
}
__global__ void dinv_kernel(const int* __restrict__ cnt, float* __restrict__ dinv, int n) {
    int i = blockIdx.x * blockDim.x + threadIdx.x;
    if (i < n) dinv[i] = rsqrtf((float)cnt[i] + 1.0f);   // +1 self loop
}

// ---------------- 3-kernel exclusive scan -> rowptr ----------------
__global__ void scan1(const int* __restrict__ cnt, int* __restrict__ excl,
                      int* __restrict__ bsum, int n) {
    __shared__ int sm[256];
    int i = blockIdx.x * 256 + threadIdx.x;
    int v = (i < n) ? cnt[i] : 0;
    sm[threadIdx.x] = v;
    __syncthreads();
#pragma unroll
    for (int off = 1; off < 256; off <<= 1) {
        int t = (threadIdx.x >= off) ? sm[threadIdx.x - off] : 0;
        __syncthreads();
        sm[threadIdx.x] += t;
        __syncthreads();
    }
    if (i < n) excl[i] = sm[threadIdx.x] - v;
    if (threadIdx.x == 255) bsum[blockIdx.x] = sm[255];
}
__global__ void scan2(int* __restrict__ bsum, int nb) {
    __shared__ int sm[256];
    int v = (threadIdx.x < nb) ? bsum[threadIdx.x] : 0;
    sm[threadIdx.x] = v;
    __syncthreads();
#pragma unroll
    for (int off = 1; off < 256; off <<= 1) {
        int t = (threadIdx.x >= off) ? sm[threadIdx.x - off] : 0;
        __syncthreads();
        sm[threadIdx.x] += t;
        __syncthreads();
    }
    if (threadIdx.x < nb) bsum[threadIdx.x] = sm[threadIdx.x] - v;
}
__global__ void scan3(int* __restrict__ rowptr, const int* __restrict__ bsum, int n, int E) {
    int i = blockIdx.x * 256 + threadIdx.x;
    if (i < n) rowptr[i] += bsum[blockIdx.x];
    if (i == 0) rowptr[n] = E;
}
__global__ void scatter_kernel(const int* __restrict__ src, const int* __restrict__ dst,
                               const int* __restrict__ rowptr, int* __restrict__ cursor,
                               int* __restrict__ esrc, int E) {
    int e = blockIdx.x * blockDim.x + threadIdx.x;
    if (e >= E) return;
    int d = dst[e];
    int p = rowptr[d] + atomicAdd(&cursor[d], 1);
    esrc[p] = src[e];
}

// ---------------- prep casts ----------------
__global__ void cast_pad_x(const float* __restrict__ x, unsigned short* __restrict__ xb) {
    long i = (long)blockIdx.x * blockDim.x + threadIdx.x;
    if (i >= (long)NN * KP1) return;
    int row = (int)(i / KP1), col = (int)(i % KP1);
    float v = (col < F_IN) ? x[(long)row * F_IN + col] : 0.f;
    xb[i] = f2b(v);
}
// Wt[n][k] = W[k][n], zero-padded to Kp
__global__ void castT_W(const float* __restrict__ W, unsigned short* __restrict__ Wt,
                        int K, int Nd, int Kp) {
    int i = blockIdx.x * blockDim.x + threadIdx.x;
    if (i >= Nd * Kp) return;
    int n = i / Kp, k = i % Kp;
    Wt[i] = f2b(k < K ? W[(long)k * Nd + n] : 0.f);
}

// ---------------- bf16 MFMA GEMM: out[M,Nd] = A[M,Ka] @ Wt[Nd,Ka]^T ----------------
template <bool BIAS_ACT, bool ROW_SCALE>
__global__ __launch_bounds__(256) void gemm_mfma(const unsigned short* __restrict__ A,
                                                 const unsigned short* __restrict__ Wt,
                                                 const float* __restrict__ bias,
                                                 const float* __restrict__ rscale,
                                                 unsigned short* __restrict__ out,
                                                 int M, int Ka, int Nd) {
    __shared__ unsigned short As[64][40];   // +8 pad breaks pow2 bank aliasing
    __shared__ unsigned short Bs[64][40];
    int tid = threadIdx.x;
    int wave = tid >> 6, lane = tid & 63;
    int lm = lane & 15, lk = lane >> 4;
    int m0 = blockIdx.x * 64, n0 = blockIdx.y * 64;
    int sr = tid >> 2, sk = (tid & 3) * 8;
    int gmS = m0 + sr;
    const unsigned short* Arow = A + (long)gmS * Ka + sk;
    const unsigned short* Brow = Wt + (long)(n0 + sr) * Ka + sk;
    floatx4 acc[4] = {};
    for (int k0 = 0; k0 < Ka; k0 += 32) {
        uint4 av = make_uint4(0, 0, 0, 0);
        if (gmS < M) av = *(const uint4*)(Arow + k0);
        uint4 bv = *(const uint4*)(Brow + k0);
        __syncthreads();
        *(uint4*)&As[sr][sk] = av;
        *(uint4*)&Bs[sr][sk] = bv;
        __syncthreads();
        short8_t af = *(const short8_t*)&As[wave * 16 + lm][lk * 8];
#pragma unroll
        for (int c = 0; c < 4; ++c) {
            short8_t bf = *(const short8_t*)&Bs[c * 16 + lm][lk * 8];
            acc[c] = __builtin_amdgcn_mfma_f32_16x16x32_bf16(af, bf, acc[c], 0, 0, 0);
        }
    }
#pragma unroll
    for (int r = 0; r < 4; ++r) {
        int gm = m0 + wave * 16 + lk * 4 + r;
        if (gm >= M) continue;
        float rs = ROW_SCALE ? rscale[gm] : 1.f;
#pragma unroll
        for (int c = 0; c < 4; ++c) {
            int gn = n0 + c * 16 + lm;
            float v = acc[c][r];
            if constexpr (BIAS_ACT) { v += bias[gn]; v = lrelu(v); }
            if constexpr (ROW_SCALE) v *= rs;
            out[(long)gm * Nd + gn] = f2b(v);
        }
    }
}

// ------- fused CSR gather + self-loop + LayerNorm + lrelu (+L2 norm): wave/node -------
// y rows are bf16, pre-scaled by dinv[src].  x = (sum_nbrs + self) * dinv[i] + bias
template <int D, bool L2N, bool TOBF>
__global__ __launch_bounds__(256) void agg_ln(const unsigned short* __restrict__ y,
                                              const int* __restrict__ rowptr,
                                              const int* __restrict__ esrc,
                                              const float* __restrict__ dinv,
                                              const float* __restrict__ bias,
                                              const float* __restrict__ gamma,
                                              const float* __restrict__ beta,
                                              unsigned short* __restrict__ outb,
                                              float* __restrict__ outf) {
    constexpr int V = D / 64;   // 4 for 256, 2 for 128
    int wave = threadIdx.x >> 6, lane = threadIdx.x & 63;
    int i = blockIdx.x * 4 + wave;
    if (i >= NN) return;
    int beg = rowptr[i], end = rowptr[i + 1];
    const long lv = (long)lane * V;
    float acc[V] = {};
    int k = beg;
    for (; k + 3 < end; k += 4) {               // x4 unroll: 4 rows in flight
        int s0 = esrc[k], s1 = esrc[k + 1], s2 = esrc[k + 2], s3 = esrc[k + 3];
        if constexpr (V == 4) {
            ushort4 r0 = *(const ushort4*)(y + (long)s0 * D + lv);
            ushort4 r1 = *(const ushort4*)(y + (long)s1 * D + lv);
            ushort4 r2 = *(const ushort4*)(y + (long)s2 * D + lv);
            ushort4 r3 = *(const ushort4*)(y + (long)s3 * D + lv);
            acc[0] += (b2f(r0.x) + b2f(r1.x)) + (b2f(r2.x) + b2f(r3.x));
            acc[1] += (b2f(r0.y) + b2f(r1.y)) + (b2f(r2.y) + b2f(r3.y));
            acc[2] += (b2f(r0.z) + b2f(r1.z)) + (b2f(r2.z) + b2f(r3.z));
            acc[3] += (b2f(r0.w) + b2f(r1.w)) + (b2f(r2.w) + b2f(r3.w));
        } else {
            ushort2 r0 = *(const ushort2*)(y + (long)s0 * D + lv);
            ushort2 r1 = *(const ushort2*)(y + (long)s1 * D + lv);
            ushort2 r2 = *(const ushort2*)(y + (long)s2 * D + lv);
            ushort2 r3 = *(const ushort2*)(y + (long)s3 * D + lv);
            acc[0] += (b2f(r0.x) + b2f(r1.x)) + (b2f(r2.x) + b2f(r3.x));
            acc[1] += (b2f(r0.y) + b2f(r1.y)) + (b2f(r2.y) + b2f(r3.y));
        }
    }
    for (; k < end; ++k) {
        int s = esrc[k];
        if constexpr (V == 4) {
            ushort4 r = *(const ushort4*)(y + (long)s * D + lv);
            acc[0] += b2f(r.x); acc[1] += b2f(r.y); acc[2] += b2f(r.z); acc[3] += b2f(r.w);
        } else {
            ushort2 r = *(const ushort2*)(y + (long)s * D + lv);
            acc[0] += b2f(r.x); acc[1] += b2f(r.y);
        }
    }
    // self loop
    if constexpr (V == 4) {
        ushort4 r = *(const ushort4*)(y + (long)i * D + lv);
        acc[0] += b2f(r.x); acc[1] += b2f(r.y); acc[2] += b2f(r.z); acc[3] += b2f(r.w);
    } else {
        ushort2 r = *(const ushort2*)(y + (long)i * D + lv);
        acc[0] += b2f(r.x); acc[1] += b2f(r.y);
    }
    float di = dinv[i];
    float xv[V], lsum = 0.f;
#pragma unroll
    for (int v = 0; v < V; ++v) { xv[v] = acc[v] * di + bias[lv + v]; lsum += xv[v]; }
    float mu = wave_allsum(lsum) * (1.0f / D);
    float l2 = 0.f;
#pragma unroll
    for (int v = 0; v < V; ++v) { xv[v] -= mu; l2 += xv[v] * xv[v]; }
    float rstd = rsqrtf(wave_allsum(l2) * (1.0f / D) + 1e-5f);
    float yv[V], ss = 0.f;
#pragma unroll
    for (int v = 0; v < V; ++v) {
        float t = xv[v] * rstd * gamma[lv + v] + beta[lv + v];
        t = lrelu(t);
        yv[v] = t; ss += t * t;
    }
    if constexpr (L2N) {
        float inv = 1.0f / fmaxf(sqrtf(wave_allsum(ss)), 1e-12f);
#pragma unroll
        for (int v = 0; v < V; ++v) yv[v] *= inv;
    }
    if constexpr (TOBF) {
        if constexpr (V == 4) {
            *(ushort4*)(outb + (long)i * D + lv) =
                make_ushort4(f2b(yv[0]), f2b(yv[1]), f2b(yv[2]), f2b(yv[3]));
        } else {
            *(ushort2*)(outb + (long)i * D + lv) = make_ushort2(f2b(yv[0]), f2b(yv[1]));
        }
    } else {
        if constexpr (V == 2) {
            *(float2*)(outf + (long)i * D + lv) = make_float2(yv[0], yv[1]);
        } else {
            *(float4*)(outf + (long)i * D + lv) = make_float4(yv[0], yv[1], yv[2], yv[3]);
        }
    }
}

// ---------- fused pool (batch is sorted -> segment sum) + MLP head: block/graph -------
__device__ __forceinline__ int lbound(const int* __restrict__ a, int n, int v) {
    int lo = 0, hi = n;
    while (lo < hi) { int mid = (lo + hi) >> 1; if (a[mid] < v) lo = mid + 1; else hi = mid; }
    return lo;
}
__global__ __launch_bounds__(128) void pool_head(const float* __restrict__ ha,
                                                 const int* __restrict__ batch,
                                                 const float* __restrict__ fc1W,
                                                 const float* __restrict__ fc1b,
                                                 const float* __restrict__ fc2W,
                                                 const float* __restrict__ fc2b,
                                                 float* __restrict__ out) {
    __shared__ float sm[D_EMB];
    int g = blockIdx.x;
    int f = threadIdx.x;  // 0..127
    int lo = lbound(batch, NN, g);
    int hi = lbound(batch, NN, g + 1);
    float acc = 0.f;
    for (int i = lo; i < hi; ++i) acc += ha[(long)i * D_EMB + f];
    sm[f] = acc;
    __syncthreads();
    if (f < 64) {
        float h = fc1b[f];
#pragma unroll 8
        for (int k2 = 0; k2 < D_EMB; ++k2) h += sm[k2] * fc1W[k2 * 64 + f];
        h = lrelu(h) * fc2W[f];
#pragma unroll
        for (int m = 1; m < 64; m <<= 1) h += __shfl_xor(h, m);
        if (f == 0) out[g] = h + fc2b[0];
    }
}

static inline size_t align256(size_t x) { return (x + 255) & ~(size_t)255; }

extern "C" void kernel_launch(void* const* d_in, const int* in_sizes, int n_in,
                              void* d_out, int out_size, void* d_ws, size_t ws_size,
                              hipStream_t stream) {
    const float* x     = (const float*)d_in[0];
    const int*   ei    = (const int*)d_in[1];
    const int*   batch = (const int*)d_in[2];
    const float* nfc_W = (const float*)d_in[3];
    const float* nfc_b = (const float*)d_in[4];
    const float* gn1_g = (const float*)d_in[5];
    const float* gn1_b = (const float*)d_in[6];
    const float* gc1_W = (const float*)d_in[7];
    const float* gc1_b = (const float*)d_in[8];
    const float* gn2_g = (const float*)d_in[9];
    const float* gn2_b = (const float*)d_in[10];
    const float* gc2_W = (const float*)d_in[11];
    const float* gc2_b = (const float*)d_in[12];
    const float* fc1_W = (const float*)d_in[13];
    const float* fc1_b = (const float*)d_in[14];
    const float* fc2_W = (const float*)d_in[15];
    const float* fc2_b = (const float*)d_in[16];

    typedef unsigned short u16;
    char* ws = (char*)d_ws;
    size_t off = 0;
    int*   cnt    = (int*)(ws + off);   off += (size_t)NN * 4;          // cnt+cursor contiguous
    int*   cursor = (int*)(ws + off);   off += align256((size_t)NN * 4);
    float* dinv   = (float*)(ws + off); off += align256((size_t)NN * 4);
    int*   rowptr = (int*)(ws + off);   off += align256((size_t)(NN + 1) * 4);
    int*   bsum   = (int*)(ws + off);   off += align256((size_t)256 * 4);
    int*   esrc   = (int*)(ws + off);   off += align256((size_t)EE * 4);
    u16*   xb     = (u16*)(ws + off);   off += align256((size_t)NN * KP1 * 2);
    u16*   WtN    = (u16*)(ws + off);   off += align256((size_t)D_H * KP1 * 2);
    u16*   Wt1    = (u16*)(ws + off);   off += align256((size_t)D_H * D_H * 2);
    u16*   Wt2    = (u16*)(ws + off);   off += align256((size_t)D_EMB * D_H * 2);
    u16*   ha1b   = (u16*)(ws + off);   off += align256((size_t)NN * D_H * 2);
    u16*   y1b    = (u16*)(ws + off);   off += align256((size_t)NN * D_H * 2);
    u16*   ha2b   = (u16*)(ws + off);   off += align256((size_t)NN * D_H * 2);
    u16*   y2b    = (u16*)(ws + off);   off += align256((size_t)NN * D_EMB * 2);

    const int* src = ei;
    const int* dst = ei + EE;
    float* out_scores = (float*)d_out;
    float* out_ha     = (float*)d_out + GG;

    const int NB = (NN + 255) / 256;
    const int MB = (NN + 63) / 64;

    // 1) CSR build + dinv
    hipMemsetAsync(cnt, 0, (size_t)NN * 8, stream);   // cnt + cursor
    count_kernel<<<(EE + 255) / 256, 256, 0, stream>>>(dst, cnt, EE);
    dinv_kernel<<<NB, 256, 0, stream>>>(cnt, dinv, NN);
    scan1<<<NB, 256, 0, stream>>>(cnt, rowptr, bsum, NN);
    scan2<<<1, 256, 0, stream>>>(bsum, NB);
    scan3<<<NB, 256, 0, stream>>>(rowptr, bsum, NN, EE);
    scatter_kernel<<<(EE + 255) / 256, 256, 0, stream>>>(src, dst, rowptr, cursor, esrc, EE);

    // 2) bf16 prep
    cast_pad_x<<<(int)(((long)NN * KP1 + 255) / 256), 256, 0, stream>>>(x, xb);
    castT_W<<<(D_H * KP1 + 255) / 256, 256, 0, stream>>>(nfc_W, WtN, F_IN, D_H, KP1);
    castT_W<<<(D_H * D_H + 255) / 256, 256, 0, stream>>>(gc1_W, Wt1, D_H, D_H, D_H);
    castT_W<<<(D_EMB * D_H + 255) / 256, 256, 0, stream>>>(gc2_W, Wt2, D_H, D_EMB, D_H);

    // 3) ha1 = lrelu(x @ nfc_W + b)   [N,256] bf16
    gemm_mfma<true, false><<<dim3(MB, D_H / 64), 256, 0, stream>>>(
        xb, WtN, nfc_b, nullptr, ha1b, NN, KP1, D_H);

    // 4) conv1: y1 = (ha1 @ gc1_W) * dinv[row]; fused agg+LN -> ha2 bf16
    gemm_mfma<false, true><<<dim3(MB, D_H / 64), 256, 0, stream>>>(
        ha1b, Wt1, nullptr, dinv, y1b, NN, D_H, D_H);
    agg_ln<D_H, false, true><<<(NN + 3) / 4, 256, 0, stream>>>(
        y1b, rowptr, esrc, dinv, gc1_b, gn1_g, gn1_b, ha2b, nullptr);

    // 5) conv2: y2 = (ha2 @ gc2_W) * dinv[row]; fused agg+LN+L2 -> out_ha fp32
    gemm_mfma<false, true><<<dim3(MB, D_EMB / 64), 256, 0, stream>>>(
        ha2b, Wt2, nullptr, dinv, y2b, NN, D_H, D_EMB);
    agg_ln<D_EMB, true, false><<<(NN + 3) / 4, 256, 0, stream>>>(
        y2b, rowptr, esrc, dinv, gc2_b, gn2_g, gn2_b, nullptr, out_ha);

    // 6) fused pool + head (batch sorted -> segment sum, no atomics)
    pool_head<<<GG, 128, 0, stream>>>(out_ha, batch, fc1_W, fc1_b, fc2_W, fc2_b, out_scores);
}

// Round 6
// 332.764 us; speedup vs baseline: 3.2342x; 1.0149x over previous
//
#include <hip/hip_runtime.h>

#define NN 50000
#define EE 400000
#define GG 500
#define F_IN 92
#define KP1 96      // F_IN padded to multiple of 32
#define D_H 256
#define D_EMB 128

typedef __attribute__((ext_vector_type(8))) short short8_t;
typedef __attribute__((ext_vector_type(4))) float floatx4;
typedef unsigned short u16;
typedef unsigned int u32;

__device__ __forceinline__ float lrelu(float v) { return v > 0.f ? v : 0.01f * v; }
__device__ __forceinline__ u16 f2b(float v) {
    union { float f; u32 u; } x; x.f = v;
    u32 r = x.u + 0x7FFFu + ((x.u >> 16) & 1u);   // RNE
    return (u16)(r >> 16);
}
__device__ __forceinline__ float wave_allsum(float v) {
#pragma unroll
    for (int m = 1; m < 64; m <<= 1) v += __shfl_xor(v, m);
    return v;
}

// ---------------- degree count ----------------
__global__ void count_kernel(const int* __restrict__ dst, int* __restrict__ cnt, int E) {
    int e = blockIdx.x * blockDim.x + threadIdx.x;
    if (e < E) atomicAdd(&cnt[dst[e]], 1);
}

// ---------------- 3-kernel exclusive scan -> rowptr (+ fused dinv) ----------------
__global__ void scan1(const int* __restrict__ cnt, int* __restrict__ excl,
                      int* __restrict__ bsum, float* __restrict__ dinv, int n) {
    __shared__ int sm[256];
    int i = blockIdx.x * 256 + threadIdx.x;
    int v = (i < n) ? cnt[i] : 0;
    if (i < n) dinv[i] = rsqrtf((float)v + 1.0f);   // +1 self loop
    sm[threadIdx.x] = v;
    __syncthreads();
#pragma unroll
    for (int off = 1; off < 256; off <<= 1) {
        int t = (threadIdx.x >= off) ? sm[threadIdx.x - off] : 0;
        __syncthreads();
        sm[threadIdx.x] += t;
        __syncthreads();
    }
    if (i < n) excl[i] = sm[threadIdx.x] - v;
    if (threadIdx.x == 255) bsum[blockIdx.x] = sm[255];
}
__global__ void scan2(int* __restrict__ bsum, int nb) {
    __shared__ int sm[256];
    int v = (threadIdx.x < nb) ? bsum[threadIdx.x] : 0;
    sm[threadIdx.x] = v;
    __syncthreads();
#pragma unroll
    for (int off = 1; off < 256; off <<= 1) {
        int t = (threadIdx.x >= off) ? sm[threadIdx.x - off] : 0;
        __syncthreads();
        sm[threadIdx.x] += t;
        __syncthreads();
    }
    if (threadIdx.x < nb) bsum[threadIdx.x] = sm[threadIdx.x] - v;
}
__global__ void scan3(int* __restrict__ rowptr, const int* __restrict__ bsum, int n, int E) {
    int i = blockIdx.x * 256 + threadIdx.x;
    if (i < n) rowptr[i] += bsum[blockIdx.x];
    if (i == 0) rowptr[n] = E;
}
__global__ void scatter_kernel(const int* __restrict__ src, const int* __restrict__ dst,
                               const int* __restrict__ rowptr, int* __restrict__ cursor,
                               int* __restrict__ esrc, int E) {
    int e = blockIdx.x * blockDim.x + threadIdx.x;
    if (e >= E) return;
    int d = dst[e];
    int p = rowptr[d] + atomicAdd(&cursor[d], 1);
    esrc[p] = src[e];
}

// ---------------- prep casts ----------------
__global__ void cast_pad_x(const float* __restrict__ x, u16* __restrict__ xb) {
    long i = (long)blockIdx.x * blockDim.x + threadIdx.x;
    if (i >= (long)NN * KP1) return;
    int row = (int)(i / KP1), col = (int)(i % KP1);
    float v = (col < F_IN) ? x[(long)row * F_IN + col] : 0.f;
    xb[i] = f2b(v);
}
__global__ void castT_W(const float* __restrict__ W, u16* __restrict__ Wt,
                        int K, int Nd, int Kp) {
    int i = blockIdx.x * blockDim.x + threadIdx.x;
    if (i >= Nd * Kp) return;
    int n = i / Kp, k = i % Kp;
    Wt[i] = f2b(k < K ? W[(long)k * Nd + n] : 0.f);
}

// ------------- bf16 MFMA GEMM: out[M,Nd] = A[M,Ka] @ Wt[Nd,Ka]^T, 128x64 tile -------
template <bool BIAS_ACT, bool ROW_SCALE>
__global__ __launch_bounds__(256) void gemm_mfma(const u16* __restrict__ A,
                                                 const u16* __restrict__ Wt,
                                                 const float* __restrict__ bias,
                                                 const float* __restrict__ rscale,
                                                 u16* __restrict__ out,
                                                 int M, int Ka, int Nd) {
    __shared__ u16 As[128][40];   // 80B row stride: MFMA frag reads are 2-way (free)
    __shared__ u16 Bs[64][40];
    int tid = threadIdx.x;
    int wave = tid >> 6, lane = tid & 63;
    int lm = lane & 15, lk = lane >> 4;
    int m0 = blockIdx.x * 128, n0 = blockIdx.y * 64;
    int rowA = tid >> 1, skA = (tid & 1) * 16;   // A tile: 128x32, 2 uint4/thread
    int rowB = tid >> 2, skB = (tid & 3) * 8;    // B tile: 64x32, 1 uint4/thread
    int gmA = m0 + rowA;
    const u16* Ap = A + (size_t)gmA * Ka + skA;
    const u16* Bp = Wt + (size_t)(n0 + rowB) * Ka + skB;
    floatx4 acc[2][4] = {};
    for (int k0 = 0; k0 < Ka; k0 += 32) {
        uint4 a0 = make_uint4(0, 0, 0, 0), a1 = make_uint4(0, 0, 0, 0);
        if (gmA < M) {
            a0 = *(const uint4*)(Ap + k0);
            a1 = *(const uint4*)(Ap + k0 + 8);
        }
        uint4 bv = *(const uint4*)(Bp + k0);
        __syncthreads();
        *(uint4*)&As[rowA][skA] = a0;
        *(uint4*)&As[rowA][skA + 8] = a1;
        *(uint4*)&Bs[rowB][skB] = bv;
        __syncthreads();
        short8_t af0 = *(const short8_t*)&As[wave * 32 + lm][lk * 8];
        short8_t af1 = *(const short8_t*)&As[wave * 32 + 16 + lm][lk * 8];
#pragma unroll
        for (int c = 0; c < 4; ++c) {
            short8_t bf = *(const short8_t*)&Bs[c * 16 + lm][lk * 8];
            acc[0][c] = __builtin_amdgcn_mfma_f32_16x16x32_bf16(af0, bf, acc[0][c], 0, 0, 0);
            acc[1][c] = __builtin_amdgcn_mfma_f32_16x16x32_bf16(af1, bf, acc[1][c], 0, 0, 0);
        }
    }
#pragma unroll
    for (int h = 0; h < 2; ++h) {
#pragma unroll
        for (int r = 0; r < 4; ++r) {
            int gm = m0 + wave * 32 + h * 16 + lk * 4 + r;
            if (gm >= M) continue;
            float rs = ROW_SCALE ? rscale[gm] : 1.f;
#pragma unroll
            for (int c = 0; c < 4; ++c) {
                int gn = n0 + c * 16 + lm;
                float v = acc[h][c][r];
                if constexpr (BIAS_ACT) { v += bias[gn]; v = lrelu(v); }
                if constexpr (ROW_SCALE) v *= rs;
                out[(size_t)gm * Nd + gn] = f2b(v);
            }
        }
    }
}

// ------- fused CSR gather + self-loop + LayerNorm + lrelu (+L2 norm): wave/node -------
// Rows loaded as dwords; lo bf16 -> f32 via u<<16, hi via u&0xFFFF0000 (1 bitop + 1 add
// per element). beg/end/esrc kept wave-uniform in SGPRs (readfirstlane -> s_load).
template <int U>
__device__ __forceinline__ void loadrow(const u32* __restrict__ p, u32* r) {
    if constexpr (U == 2) { uint2 t = *(const uint2*)p; r[0] = t.x; r[1] = t.y; }
    else                  { r[0] = *p; }
}
template <int D, bool L2N, bool TOBF>
__global__ __launch_bounds__(256) void agg_ln(const u16* __restrict__ y,
                                              const int* __restrict__ rowptr,
                                              const int* __restrict__ esrc,
                                              const float* __restrict__ dinv,
                                              const float* __restrict__ bias,
                                              const float* __restrict__ gamma,
                                              const float* __restrict__ beta,
                                              u16* __restrict__ outb,
                                              float* __restrict__ outf) {
    constexpr int V = D / 64;    // elems per lane (4 / 2)
    constexpr int U = V / 2;     // dwords per lane (2 / 1)
    constexpr int RW = D / 2;    // dwords per row
    int wave = threadIdx.x >> 6, lane = threadIdx.x & 63;
    int i = blockIdx.x * 4 + wave;           // NN % 4 == 0: all waves full
    if (i >= NN) return;
    int beg = __builtin_amdgcn_readfirstlane(rowptr[i]);
    int end = __builtin_amdgcn_readfirstlane(rowptr[i + 1]);
    const u32* yu = (const u32*)y;
    const int lu = lane * U;
    float accL[U] = {}, accH[U] = {};
    u32 r0[U], r1[U], r2[U], r3[U];
    int k = beg;
    for (; k + 3 < end; k += 4) {            // 4 rows in flight
        int s0 = esrc[k], s1 = esrc[k + 1], s2 = esrc[k + 2], s3 = esrc[k + 3];
        loadrow<U>(yu + (size_t)s0 * RW + lu, r0);
        loadrow<U>(yu + (size_t)s1 * RW + lu, r1);
        loadrow<U>(yu + (size_t)s2 * RW + lu, r2);
        loadrow<U>(yu + (size_t)s3 * RW + lu, r3);
#pragma unroll
        for (int j = 0; j < U; ++j) {
            accL[j] += (__uint_as_float(r0[j] << 16) + __uint_as_float(r1[j] << 16))
                     + (__uint_as_float(r2[j] << 16) + __uint_as_float(r3[j] << 16));
            accH[j] += (__uint_as_float(r0[j] & 0xFFFF0000u) + __uint_as_float(r1[j] & 0xFFFF0000u))
                     + (__uint_as_float(r2[j] & 0xFFFF0000u) + __uint_as_float(r3[j] & 0xFFFF0000u));
        }
    }
    for (; k < end; ++k) {
        int s = esrc[k];
        loadrow<U>(yu + (size_t)s * RW + lu, r0);
#pragma unroll
        for (int j = 0; j < U; ++j) {
            accL[j] += __uint_as_float(r0[j] << 16);
            accH[j] += __uint_as_float(r0[j] & 0xFFFF0000u);
        }
    }
    // self loop
    loadrow<U>(yu + (size_t)i * RW + lu, r0);
#pragma unroll
    for (int j = 0; j < U; ++j) {
        accL[j] += __uint_as_float(r0[j] << 16);
        accH[j] += __uint_as_float(r0[j] & 0xFFFF0000u);
    }
    float di = dinv[i];
    float xv[V], lsum = 0.f;
#pragma unroll
    for (int j = 0; j < U; ++j) {
        xv[2 * j]     = accL[j] * di + bias[lane * V + 2 * j];
        xv[2 * j + 1] = accH[j] * di + bias[lane * V + 2 * j + 1];
    }
#pragma unroll
    for (int v = 0; v < V; ++v) lsum += xv[v];
    float mu = wave_allsum(lsum) * (1.0f / D);
    float l2 = 0.f;
#pragma unroll
    for (int v = 0; v < V; ++v) { xv[v] -= mu; l2 += xv[v] * xv[v]; }
    float rstd = rsqrtf(wave_allsum(l2) * (1.0f / D) + 1e-5f);
    float yv[V], ss = 0.f;
#pragma unroll
    for (int v = 0; v < V; ++v) {
        float t = xv[v] * rstd * gamma[lane * V + v] + beta[lane * V + v];
        t = lrelu(t);
        yv[v] = t; ss += t * t;
    }
    if constexpr (L2N) {
        float inv = 1.0f / fmaxf(sqrtf(wave_allsum(ss)), 1e-12f);
#pragma unroll
        for (int v = 0; v < V; ++v) yv[v] *= inv;
    }
    if constexpr (TOBF) {
        if constexpr (V == 4) {
            *(ushort4*)(outb + (size_t)i * D + lane * V) =
                make_ushort4(f2b(yv[0]), f2b(yv[1]), f2b(yv[2]), f2b(yv[3]));
        } else {
            *(ushort2*)(outb + (size_t)i * D + lane * V) = make_ushort2(f2b(yv[0]), f2b(yv[1]));
        }
    } else {
        if constexpr (V == 2) {
            *(float2*)(outf + (size_t)i * D + lane * V) = make_float2(yv[0], yv[1]);
        } else {
            *(float4*)(outf + (size_t)i * D + lane * V) = make_float4(yv[0], yv[1], yv[2], yv[3]);
        }
    }
}

// ---------- fused pool (batch sorted -> segment sum) + MLP head: block/graph -------
__device__ __forceinline__ int lbound(const int* __restrict__ a, int n, int v) {
    int lo = 0, hi = n;
    while (lo < hi) { int mid = (lo + hi) >> 1; if (a[mid] < v) lo = mid + 1; else hi = mid; }
    return lo;
}
__global__ __launch_bounds__(128) void pool_head(const float* __restrict__ ha,
                                                 const int* __restrict__ batch,
                                                 const float* __restrict__ fc1W,
                                                 const float* __restrict__ fc1b,
                                                 const float* __restrict__ fc2W,
                                                 const float* __restrict__ fc2b,
                                                 float* __restrict__ out) {
    __shared__ float sm[D_EMB];
    int g = blockIdx.x;
    int f = threadIdx.x;  // 0..127
    int lo = lbound(batch, NN, g);
    int hi = lbound(batch, NN, g + 1);
    float acc = 0.f;
    for (int i = lo; i < hi; ++i) acc += ha[(long)i * D_EMB + f];
    sm[f] = acc;
    __syncthreads();
    if (f < 64) {
        float h = fc1b[f];
#pragma unroll 8
        for (int k2 = 0; k2 < D_EMB; ++k2) h += sm[k2] * fc1W[k2 * 64 + f];
        h = lrelu(h) * fc2W[f];
#pragma unroll
        for (int m = 1; m < 64; m <<= 1) h += __shfl_xor(h, m);
        if (f == 0) out[g] = h + fc2b[0];
    }
}

static inline size_t align256(size_t x) { return (x + 255) & ~(size_t)255; }

extern "C" void kernel_launch(void* const* d_in, const int* in_sizes, int n_in,
                              void* d_out, int out_size, void* d_ws, size_t ws_size,
                              hipStream_t stream) {
    const float* x     = (const float*)d_in[0];
    const int*   ei    = (const int*)d_in[1];
    const int*   batch = (const int*)d_in[2];
    const float* nfc_W = (const float*)d_in[3];
    const float* nfc_b = (const float*)d_in[4];
    const float* gn1_g = (const float*)d_in[5];
    const float* gn1_b = (const float*)d_in[6];
    const float* gc1_W = (const float*)d_in[7];
    const float* gc1_b = (const float*)d_in[8];
    const float* gn2_g = (const float*)d_in[9];
    const float* gn2_b = (const float*)d_in[10];
    const float* gc2_W = (const float*)d_in[11];
    const float* gc2_b = (const float*)d_in[12];
    const float* fc1_W = (const float*)d_in[13];
    const float* fc1_b = (const float*)d_in[14];
    const float* fc2_W = (const float*)d_in[15];
    const float* fc2_b = (const float*)d_in[16];

    char* ws = (char*)d_ws;
    size_t off = 0;
    int*   cnt    = (int*)(ws + off);   off += (size_t)NN * 4;   // cnt+cursor contiguous
    int*   cursor = (int*)(ws + off);   off += align256((size_t)NN * 4);
    float* dinv   = (float*)(ws + off); off += align256((size_t)NN * 4);
    int*   rowptr = (int*)(ws + off);   off += align256((size_t)(NN + 1) * 4);
    int*   bsum   = (int*)(ws + off);   off += align256((size_t)256 * 4);
    int*   esrc   = (int*)(ws + off);   off += align256((size_t)EE * 4);
    u16*   xb     = (u16*)(ws + off);   off += align256((size_t)NN * KP1 * 2);
    u16*   WtN    = (u16*)(ws + off);   off += align256((size_t)D_H * KP1 * 2);
    u16*   Wt1    = (u16*)(ws + off);   off += align256((size_t)D_H * D_H * 2);
    u16*   Wt2    = (u16*)(ws + off);   off += align256((size_t)D_EMB * D_H * 2);
    u16*   ha1b   = (u16*)(ws + off);   off += align256((size_t)NN * D_H * 2);
    u16*   y1b    = (u16*)(ws + off);   off += align256((size_t)NN * D_H * 2);
    u16*   ha2b   = (u16*)(ws + off);   off += align256((size_t)NN * D_H * 2);
    u16*   y2b    = (u16*)(ws + off);   off += align256((size_t)NN * D_EMB * 2);

    const int* src = ei;
    const int* dst = ei + EE;
    float* out_scores = (float*)d_out;
    float* out_ha     = (float*)d_out + GG;

    const int NB = (NN + 255) / 256;
    const int MB = (NN + 127) / 128;   // 391

    // 1) CSR build + dinv
    hipMemsetAsync(cnt, 0, (size_t)NN * 8, stream);   // cnt + cursor
    count_kernel<<<(EE + 255) / 256, 256, 0, stream>>>(dst, cnt, EE);
    scan1<<<NB, 256, 0, stream>>>(cnt, rowptr, bsum, dinv, NN);
    scan2<<<1, 256, 0, stream>>>(bsum, NB);
    scan3<<<NB, 256, 0, stream>>>(rowptr, bsum, NN, EE);
    scatter_kernel<<<(EE + 255) / 256, 256, 0, stream>>>(src, dst, rowptr, cursor, esrc, EE);

    // 2) bf16 prep
    cast_pad_x<<<(int)(((long)NN * KP1 + 255) / 256), 256, 0, stream>>>(x, xb);
    castT_W<<<(D_H * KP1 + 255) / 256, 256, 0, stream>>>(nfc_W, WtN, F_IN, D_H, KP1);
    castT_W<<<(D_H * D_H + 255) / 256, 256, 0, stream>>>(gc1_W, Wt1, D_H, D_H, D_H);
    castT_W<<<(D_EMB * D_H + 255) / 256, 256, 0, stream>>>(gc2_W, Wt2, D_H, D_EMB, D_H);

    // 3) ha1 = lrelu(x @ nfc_W + b)   [N,256] bf16
    gemm_mfma<true, false><<<dim3(MB, D_H / 64), 256, 0, stream>>>(
        xb, WtN, nfc_b, nullptr, ha1b, NN, KP1, D_H);

    // 4) conv1: y1 = (ha1 @ gc1_W) * dinv[row]; fused agg+LN -> ha2 bf16
    gemm_mfma<false, true><<<dim3(MB, D_H / 64), 256, 0, stream>>>(
        ha1b, Wt1, nullptr, dinv, y1b, NN, D_H, D_H);
    agg_ln<D_H, false, true><<<NN / 4, 256, 0, stream>>>(
        y1b, rowptr, esrc, dinv, gc1_b, gn1_g, gn1_b, ha2b, nullptr);

    // 5) conv2: y2 = (ha2 @ gc2_W) * dinv[row]; fused agg+LN+L2 -> out_ha fp32
    gemm_mfma<false, true><<<dim3(MB, D_EMB / 64), 256, 0, stream>>>(
        ha2b, Wt2, nullptr, dinv, y2b, NN, D_H, D_EMB);
    agg_ln<D_EMB, true, false><<<NN / 4, 256, 0, stream>>>(
        y2b, rowptr, esrc, dinv, gc2_b, gn2_g, gn2_b, nullptr, out_ha);

    // 6) fused pool + head
    pool_head<<<GG, 128, 0, stream>>>(out_ha, batch, fc1_W, fc1_b, fc2_W, fc2_b, out_scores);
}

// Round 7
// 306.449 us; speedup vs baseline: 3.5119x; 1.0859x over previous
//
#include <hip/hip_runtime.h>

#define NN 50000
#define EE 400000
#define GG 500
#define F_IN 92
#define KP1 96      // F_IN padded to multiple of 32
#define D_H 256
#define D_EMB 128
#define PCH 16      // pool rows per block

typedef __attribute__((ext_vector_type(8))) short short8_t;
typedef __attribute__((ext_vector_type(4))) float floatx4;
typedef unsigned short u16;
typedef unsigned int u32;

__device__ __forceinline__ float lrelu(float v) { return v > 0.f ? v : 0.01f * v; }
__device__ __forceinline__ u16 f2b(float v) {
    union { float f; u32 u; } x; x.f = v;
    u32 r = x.u + 0x7FFFu + ((x.u >> 16) & 1u);   // RNE
    return (u16)(r >> 16);
}
__device__ __forceinline__ float wave_allsum(float v) {
#pragma unroll
    for (int m = 1; m < 64; m <<= 1) v += __shfl_xor(v, m);
    return v;
}

// ---------------- degree count ----------------
__global__ void count_kernel(const int* __restrict__ dst, int* __restrict__ cnt, int E) {
    int e = blockIdx.x * blockDim.x + threadIdx.x;
    if (e < E) atomicAdd(&cnt[dst[e]], 1);
}

// ---------------- 3-kernel exclusive scan -> rowptr (+ fused dinv) ----------------
__global__ void scan1(const int* __restrict__ cnt, int* __restrict__ excl,
                      int* __restrict__ bsum, float* __restrict__ dinv, int n) {
    __shared__ int sm[256];
    int i = blockIdx.x * 256 + threadIdx.x;
    int v = (i < n) ? cnt[i] : 0;
    if (i < n) dinv[i] = rsqrtf((float)v + 1.0f);   // +1 self loop
    sm[threadIdx.x] = v;
    __syncthreads();
#pragma unroll
    for (int off = 1; off < 256; off <<= 1) {
        int t = (threadIdx.x >= off) ? sm[threadIdx.x - off] : 0;
        __syncthreads();
        sm[threadIdx.x] += t;
        __syncthreads();
    }
    if (i < n) excl[i] = sm[threadIdx.x] - v;
    if (threadIdx.x == 255) bsum[blockIdx.x] = sm[255];
}
__global__ void scan2(int* __restrict__ bsum, int nb) {
    __shared__ int sm[256];
    int v = (threadIdx.x < nb) ? bsum[threadIdx.x] : 0;
    sm[threadIdx.x] = v;
    __syncthreads();
#pragma unroll
    for (int off = 1; off < 256; off <<= 1) {
        int t = (threadIdx.x >= off) ? sm[threadIdx.x - off] : 0;
        __syncthreads();
        sm[threadIdx.x] += t;
        __syncthreads();
    }
    if (threadIdx.x < nb) bsum[threadIdx.x] = sm[threadIdx.x] - v;
}
__global__ void scan3(int* __restrict__ rowptr, const int* __restrict__ bsum, int n, int E) {
    int i = blockIdx.x * 256 + threadIdx.x;
    if (i < n) rowptr[i] += bsum[blockIdx.x];
    if (i == 0) rowptr[n] = E;
}
__global__ void scatter_kernel(const int* __restrict__ src, const int* __restrict__ dst,
                               const int* __restrict__ rowptr, int* __restrict__ cursor,
                               int* __restrict__ esrc, int E) {
    int e = blockIdx.x * blockDim.x + threadIdx.x;
    if (e >= E) return;
    int d = dst[e];
    int p = rowptr[d] + atomicAdd(&cursor[d], 1);
    esrc[p] = src[e];
}

// ---------------- prep casts ----------------
__global__ void cast_pad_x(const float* __restrict__ x, u16* __restrict__ xb) {
    long i = (long)blockIdx.x * blockDim.x + threadIdx.x;
    if (i >= (long)NN * KP1) return;
    int row = (int)(i / KP1), col = (int)(i % KP1);
    float v = (col < F_IN) ? x[(long)row * F_IN + col] : 0.f;
    xb[i] = f2b(v);
}
__global__ void castT_W(const float* __restrict__ W, u16* __restrict__ Wt,
                        int K, int Nd, int Kp) {
    int i = blockIdx.x * blockDim.x + threadIdx.x;
    if (i >= Nd * Kp) return;
    int n = i / Kp, k = i % Kp;
    Wt[i] = f2b(k < K ? W[(long)k * Nd + n] : 0.f);
}

// ------------- bf16 MFMA GEMM: out[M,Nd] = A[M,Ka] @ Wt[Nd,Ka]^T, 128x64 tile -------
template <bool BIAS_ACT, bool ROW_SCALE>
__global__ __launch_bounds__(256) void gemm_mfma(const u16* __restrict__ A,
                                                 const u16* __restrict__ Wt,
                                                 const float* __restrict__ bias,
                                                 const float* __restrict__ rscale,
                                                 u16* __restrict__ out,
                                                 int M, int Ka, int Nd) {
    __shared__ u16 As[128][40];
    __shared__ u16 Bs[64][40];
    int tid = threadIdx.x;
    int wave = tid >> 6, lane = tid & 63;
    int lm = lane & 15, lk = lane >> 4;
    int m0 = blockIdx.x * 128, n0 = blockIdx.y * 64;
    int rowA = tid >> 1, skA = (tid & 1) * 16;
    int rowB = tid >> 2, skB = (tid & 3) * 8;
    int gmA = m0 + rowA;
    const u16* Ap = A + (size_t)gmA * Ka + skA;
    const u16* Bp = Wt + (size_t)(n0 + rowB) * Ka + skB;
    floatx4 acc[2][4] = {};
    for (int k0 = 0; k0 < Ka; k0 += 32) {
        uint4 a0 = make_uint4(0, 0, 0, 0), a1 = make_uint4(0, 0, 0, 0);
        if (gmA < M) {
            a0 = *(const uint4*)(Ap + k0);
            a1 = *(const uint4*)(Ap + k0 + 8);
        }
        uint4 bv = *(const uint4*)(Bp + k0);
        __syncthreads();
        *(uint4*)&As[rowA][skA] = a0;
        *(uint4*)&As[rowA][skA + 8] = a1;
        *(uint4*)&Bs[rowB][skB] = bv;
        __syncthreads();
        short8_t af0 = *(const short8_t*)&As[wave * 32 + lm][lk * 8];
        short8_t af1 = *(const short8_t*)&As[wave * 32 + 16 + lm][lk * 8];
#pragma unroll
        for (int c = 0; c < 4; ++c) {
            short8_t bf = *(const short8_t*)&Bs[c * 16 + lm][lk * 8];
            acc[0][c] = __builtin_amdgcn_mfma_f32_16x16x32_bf16(af0, bf, acc[0][c], 0, 0, 0);
            acc[1][c] = __builtin_amdgcn_mfma_f32_16x16x32_bf16(af1, bf, acc[1][c], 0, 0, 0);
        }
    }
#pragma unroll
    for (int h = 0; h < 2; ++h) {
#pragma unroll
        for (int r = 0; r < 4; ++r) {
            int gm = m0 + wave * 32 + h * 16 + lk * 4 + r;
            if (gm >= M) continue;
            float rs = ROW_SCALE ? rscale[gm] : 1.f;
#pragma unroll
            for (int c = 0; c < 4; ++c) {
                int gn = n0 + c * 16 + lm;
                float v = acc[h][c][r];
                if constexpr (BIAS_ACT) { v += bias[gn]; v = lrelu(v); }
                if constexpr (ROW_SCALE) v *= rs;
                out[(size_t)gm * Nd + gn] = f2b(v);
            }
        }
    }
}

// ------- fused CSR gather + self-loop + LayerNorm + lrelu (+L2 norm): wave/node -------
template <int U>
__device__ __forceinline__ void loadrow(const u32* __restrict__ p, u32* r) {
    if constexpr (U == 2) { uint2 t = *(const uint2*)p; r[0] = t.x; r[1] = t.y; }
    else                  { r[0] = *p; }
}
template <int D, bool L2N, bool TOBF>
__global__ __launch_bounds__(256) void agg_ln(const u16* __restrict__ y,
                                              const int* __restrict__ rowptr,
                                              const int* __restrict__ esrc,
                                              const float* __restrict__ dinv,
                                              const float* __restrict__ bias,
                                              const float* __restrict__ gamma,
                                              const float* __restrict__ beta,
                                              u16* __restrict__ outb,
                                              float* __restrict__ outf) {
    constexpr int V = D / 64;    // elems per lane (4 / 2)
    constexpr int U = V / 2;     // dwords per lane (2 / 1)
    constexpr int RW = D / 2;    // dwords per row
    int wave = threadIdx.x >> 6, lane = threadIdx.x & 63;
    int i = blockIdx.x * 4 + wave;           // NN % 4 == 0
    if (i >= NN) return;
    int beg = __builtin_amdgcn_readfirstlane(rowptr[i]);
    int end = __builtin_amdgcn_readfirstlane(rowptr[i + 1]);
    const u32* yu = (const u32*)y;
    const int lu = lane * U;
    float accL[U] = {}, accH[U] = {};
    u32 r[8][U];
    int k = beg;
    for (; k + 7 < end; k += 8) {            // 8 rows in flight (mean degree = 8)
#pragma unroll
        for (int q = 0; q < 8; ++q) loadrow<U>(yu + (size_t)esrc[k + q] * RW + lu, r[q]);
#pragma unroll
        for (int j = 0; j < U; ++j) {
            float sL = 0.f, sH = 0.f;
#pragma unroll
            for (int q = 0; q < 8; ++q) {
                sL += __uint_as_float(r[q][j] << 16);
                sH += __uint_as_float(r[q][j] & 0xFFFF0000u);
            }
            accL[j] += sL; accH[j] += sH;
        }
    }
    for (; k + 3 < end; k += 4) {
#pragma unroll
        for (int q = 0; q < 4; ++q) loadrow<U>(yu + (size_t)esrc[k + q] * RW + lu, r[q]);
#pragma unroll
        for (int j = 0; j < U; ++j) {
            accL[j] += (__uint_as_float(r[0][j] << 16) + __uint_as_float(r[1][j] << 16))
                     + (__uint_as_float(r[2][j] << 16) + __uint_as_float(r[3][j] << 16));
            accH[j] += (__uint_as_float(r[0][j] & 0xFFFF0000u) + __uint_as_float(r[1][j] & 0xFFFF0000u))
                     + (__uint_as_float(r[2][j] & 0xFFFF0000u) + __uint_as_float(r[3][j] & 0xFFFF0000u));
        }
    }
    for (; k < end; ++k) {
        loadrow<U>(yu + (size_t)esrc[k] * RW + lu, r[0]);
#pragma unroll
        for (int j = 0; j < U; ++j) {
            accL[j] += __uint_as_float(r[0][j] << 16);
            accH[j] += __uint_as_float(r[0][j] & 0xFFFF0000u);
        }
    }
    // self loop
    loadrow<U>(yu + (size_t)i * RW + lu, r[0]);
#pragma unroll
    for (int j = 0; j < U; ++j) {
        accL[j] += __uint_as_float(r[0][j] << 16);
        accH[j] += __uint_as_float(r[0][j] & 0xFFFF0000u);
    }
    float di = dinv[i];
    float xv[V], lsum = 0.f;
#pragma unroll
    for (int j = 0; j < U; ++j) {
        xv[2 * j]     = accL[j] * di + bias[lane * V + 2 * j];
        xv[2 * j + 1] = accH[j] * di + bias[lane * V + 2 * j + 1];
    }
#pragma unroll
    for (int v = 0; v < V; ++v) lsum += xv[v];
    float mu = wave_allsum(lsum) * (1.0f / D);
    float l2 = 0.f;
#pragma unroll
    for (int v = 0; v < V; ++v) { xv[v] -= mu; l2 += xv[v] * xv[v]; }
    float rstd = rsqrtf(wave_allsum(l2) * (1.0f / D) + 1e-5f);
    float yv[V], ss = 0.f;
#pragma unroll
    for (int v = 0; v < V; ++v) {
        float t = xv[v] * rstd * gamma[lane * V + v] + beta[lane * V + v];
        t = lrelu(t);
        yv[v] = t; ss += t * t;
    }
    if constexpr (L2N) {
        float inv = 1.0f / fmaxf(sqrtf(wave_allsum(ss)), 1e-12f);
#pragma unroll
        for (int v = 0; v < V; ++v) yv[v] *= inv;
    }
    if constexpr (TOBF) {
        if constexpr (V == 4) {
            *(ushort4*)(outb + (size_t)i * D + lane * V) =
                make_ushort4(f2b(yv[0]), f2b(yv[1]), f2b(yv[2]), f2b(yv[3]));
        } else {
            *(ushort2*)(outb + (size_t)i * D + lane * V) = make_ushort2(f2b(yv[0]), f2b(yv[1]));
        }
    } else {
        if constexpr (V == 2) {
            *(float2*)(outf + (size_t)i * D + lane * V) = make_float2(yv[0], yv[1]);
        } else {
            *(float4*)(outf + (size_t)i * D + lane * V) = make_float4(yv[0], yv[1], yv[2], yv[3]);
        }
    }
}

// ---------- pool stage 1: PCH rows per block, run-flush atomics (batch sorted) -------
__global__ __launch_bounds__(128) void pool_partial(const float* __restrict__ ha,
                                                    const int* __restrict__ batch,
                                                    float* __restrict__ hg) {
    int r0 = blockIdx.x * PCH;
    int f = threadIdx.x;
    int end = min(r0 + PCH, NN);
    int cur = batch[r0];
    float acc = 0.f;
    for (int i = r0; i < end; ++i) {
        int b = batch[i];
        if (b != cur) {
            atomicAdd(&hg[(size_t)cur * D_EMB + f], acc);
            acc = 0.f; cur = b;
        }
        acc += ha[(size_t)i * D_EMB + f];
    }
    atomicAdd(&hg[(size_t)cur * D_EMB + f], acc);
}

// ---------- head MLP: one block (64 threads) per graph on pooled hg ----------
__global__ __launch_bounds__(64) void head_kernel(const float* __restrict__ hg,
                                                  const float* __restrict__ fc1W,
                                                  const float* __restrict__ fc1b,
                                                  const float* __restrict__ fc2W,
                                                  const float* __restrict__ fc2b,
                                                  float* __restrict__ out) {
    int g = blockIdx.x;
    int j = threadIdx.x;  // 0..63
    float h = fc1b[j];
#pragma unroll 8
    for (int k = 0; k < D_EMB; ++k) h += hg[(size_t)g * D_EMB + k] * fc1W[k * 64 + j];
    h = lrelu(h) * fc2W[j];
#pragma unroll
    for (int m = 1; m < 64; m <<= 1) h += __shfl_xor(h, m);
    if (j == 0) out[g] = h + fc2b[0];
}

static inline size_t align256(size_t x) { return (x + 255) & ~(size_t)255; }

extern "C" void kernel_launch(void* const* d_in, const int* in_sizes, int n_in,
                              void* d_out, int out_size, void* d_ws, size_t ws_size,
                              hipStream_t stream) {
    const float* x     = (const float*)d_in[0];
    const int*   ei    = (const int*)d_in[1];
    const int*   batch = (const int*)d_in[2];
    const float* nfc_W = (const float*)d_in[3];
    const float* nfc_b = (const float*)d_in[4];
    const float* gn1_g = (const float*)d_in[5];
    const float* gn1_b = (const float*)d_in[6];
    const float* gc1_W = (const float*)d_in[7];
    const float* gc1_b = (const float*)d_in[8];
    const float* gn2_g = (const float*)d_in[9];
    const float* gn2_b = (const float*)d_in[10];
    const float* gc2_W = (const float*)d_in[11];
    const float* gc2_b = (const float*)d_in[12];
    const float* fc1_W = (const float*)d_in[13];
    const float* fc1_b = (const float*)d_in[14];
    const float* fc2_W = (const float*)d_in[15];
    const float* fc2_b = (const float*)d_in[16];

    char* ws = (char*)d_ws;
    size_t off = 0;
    int*   cnt    = (int*)(ws + off);   off += (size_t)NN * 4;   // cnt+cursor contiguous
    int*   cursor = (int*)(ws + off);   off += align256((size_t)NN * 4);
    float* dinv   = (float*)(ws + off); off += align256((size_t)NN * 4);
    int*   rowptr = (int*)(ws + off);   off += align256((size_t)(NN + 1) * 4);
    int*   bsum   = (int*)(ws + off);   off += align256((size_t)256 * 4);
    int*   esrc   = (int*)(ws + off);   off += align256((size_t)EE * 4);
    float* hg     = (float*)(ws + off); off += align256((size_t)GG * D_EMB * 4);
    u16*   xb     = (u16*)(ws + off);   off += align256((size_t)NN * KP1 * 2);
    u16*   WtN    = (u16*)(ws + off);   off += align256((size_t)D_H * KP1 * 2);
    u16*   Wt1    = (u16*)(ws + off);   off += align256((size_t)D_H * D_H * 2);
    u16*   Wt2    = (u16*)(ws + off);   off += align256((size_t)D_EMB * D_H * 2);
    u16*   ha1b   = (u16*)(ws + off);   off += align256((size_t)NN * D_H * 2);
    u16*   y1b    = (u16*)(ws + off);   off += align256((size_t)NN * D_H * 2);
    u16*   ha2b   = (u16*)(ws + off);   off += align256((size_t)NN * D_H * 2);
    u16*   y2b    = (u16*)(ws + off);   off += align256((size_t)NN * D_EMB * 2);

    const int* src = ei;
    const int* dst = ei + EE;
    float* out_scores = (float*)d_out;
    float* out_ha     = (float*)d_out + GG;

    const int NB = (NN + 255) / 256;
    const int MB = (NN + 127) / 128;

    // 1) CSR build + dinv (+ zero hg for pool atomics)
    hipMemsetAsync(cnt, 0, (size_t)NN * 8, stream);   // cnt + cursor
    hipMemsetAsync(hg, 0, (size_t)GG * D_EMB * 4, stream);
    count_kernel<<<(EE + 255) / 256, 256, 0, stream>>>(dst, cnt, EE);
    scan1<<<NB, 256, 0, stream>>>(cnt, rowptr, bsum, dinv, NN);
    scan2<<<1, 256, 0, stream>>>(bsum, NB);
    scan3<<<NB, 256, 0, stream>>>(rowptr, bsum, NN, EE);
    scatter_kernel<<<(EE + 255) / 256, 256, 0, stream>>>(src, dst, rowptr, cursor, esrc, EE);

    // 2) bf16 prep
    cast_pad_x<<<(int)(((long)NN * KP1 + 255) / 256), 256, 0, stream>>>(x, xb);
    castT_W<<<(D_H * KP1 + 255) / 256, 256, 0, stream>>>(nfc_W, WtN, F_IN, D_H, KP1);
    castT_W<<<(D_H * D_H + 255) / 256, 256, 0, stream>>>(gc1_W, Wt1, D_H, D_H, D_H);
    castT_W<<<(D_EMB * D_H + 255) / 256, 256, 0, stream>>>(gc2_W, Wt2, D_H, D_EMB, D_H);

    // 3) ha1 = lrelu(x @ nfc_W + b)   [N,256] bf16
    gemm_mfma<true, false><<<dim3(MB, D_H / 64), 256, 0, stream>>>(
        xb, WtN, nfc_b, nullptr, ha1b, NN, KP1, D_H);

    // 4) conv1: y1 = (ha1 @ gc1_W) * dinv[row]; fused agg+LN -> ha2 bf16
    gemm_mfma<false, true><<<dim3(MB, D_H / 64), 256, 0, stream>>>(
        ha1b, Wt1, nullptr, dinv, y1b, NN, D_H, D_H);
    agg_ln<D_H, false, true><<<NN / 4, 256, 0, stream>>>(
        y1b, rowptr, esrc, dinv, gc1_b, gn1_g, gn1_b, ha2b, nullptr);

    // 5) conv2: y2 = (ha2 @ gc2_W) * dinv[row]; fused agg+LN+L2 -> out_ha fp32
    gemm_mfma<false, true><<<dim3(MB, D_EMB / 64), 256, 0, stream>>>(
        ha2b, Wt2, nullptr, dinv, y2b, NN, D_H, D_EMB);
    agg_ln<D_EMB, true, false><<<NN / 4, 256, 0, stream>>>(
        y2b, rowptr, esrc, dinv, gc2_b, gn2_g, gn2_b, nullptr, out_ha);

    // 6) parallel pool + tiny head
    pool_partial<<<(NN + PCH - 1) / PCH, 128, 0, stream>>>(out_ha, batch, hg);
    head_kernel<<<GG, 64, 0, stream>>>(hg, fc1_W, fc1_b, fc2_W, fc2_b, out_scores);
}